// Round 1
// baseline (238.035 us; speedup 1.0000x reference)
//
#include <hip/hip_runtime.h>
#include <hip/hip_bf16.h>
#include <math.h>

typedef float f32x4 __attribute__((ext_vector_type(4)));
typedef __bf16 bf16x8 __attribute__((ext_vector_type(8)));

#define DEVFN static __device__ __forceinline__

DEVFN void gload16(const void* g, void* l) {
  __builtin_amdgcn_global_load_lds(
      (const __attribute__((address_space(1))) unsigned int*)g,
      (__attribute__((address_space(3))) unsigned int*)l, 16, 0, 0);
}

DEVFN f32x4 mfma16(bf16x8 a, bf16x8 b, f32x4 c) {
  return __builtin_amdgcn_mfma_f32_16x16x32_bf16(a, b, c, 0, 0, 0);
}

// ---------------- kernel 1: cast weights to bf16 ----------------
__global__ __launch_bounds__(256) void cast_weights_k(
    const float* __restrict__ wp, const float* __restrict__ wo,
    __bf16* __restrict__ wpb, __bf16* __restrict__ wob) {
  int i = blockIdx.x * 256 + threadIdx.x;  // total 1536*512 + 512*512 = 1048576
  if (i < 1536 * 512) {
    wpb[i] = (__bf16)wp[i];
  } else {
    int j = i - 1536 * 512;
    wob[j] = (__bf16)wo[j];
  }
}

// ---------------- kernel 2: transpose+cast x [B,C,S] f32 -> xt [B,S,C] bf16 ----
__global__ __launch_bounds__(256) void transpose_x_k(const float* __restrict__ x,
                                                     __bf16* __restrict__ xt) {
  __shared__ float tile[64][65];
  int b = blockIdx.z, c0 = blockIdx.y * 64, s0 = blockIdx.x * 64;
  int t = threadIdx.x;
  int r = t >> 2, q = (t & 3) << 4;
  const float* src = x + ((size_t)(b * 512 + c0 + r)) * 1024 + s0 + q;
#pragma unroll
  for (int i = 0; i < 4; i++) {
    float4 f = *reinterpret_cast<const float4*>(src + i * 4);
    tile[r][q + i * 4 + 0] = f.x;
    tile[r][q + i * 4 + 1] = f.y;
    tile[r][q + i * 4 + 2] = f.z;
    tile[r][q + i * 4 + 3] = f.w;
  }
  __syncthreads();
  bf16x8 o0, o1;
#pragma unroll
  for (int i = 0; i < 8; i++) o0[i] = (__bf16)tile[q + i][r];
#pragma unroll
  for (int i = 0; i < 8; i++) o1[i] = (__bf16)tile[q + 8 + i][r];
  __bf16* dst = xt + ((size_t)(b * 1024 + s0 + r)) * 512 + c0 + q;
  *reinterpret_cast<bf16x8*>(dst) = o0;
  *reinterpret_cast<bf16x8*>(dst + 8) = o1;
}

// ---------------- GEMM: C[m][n] = sum_k A[m][k]*Bt[n][k], K=512 ----------------
// MODE 0: write bf16 C.  MODE 1: write f32 C + Xres (residual), per-batch z.
template <int MODE>
__global__ __launch_bounds__(256) void gemm_bt_k(
    const __bf16* __restrict__ A, const __bf16* __restrict__ Bt,
    __bf16* __restrict__ Cb, float* __restrict__ Cf, const float* __restrict__ Xres,
    int ldc, long bstride_bt, long bstride_c) {
  __shared__ __attribute__((aligned(16))) __bf16 As[128 * 32];
  __shared__ __attribute__((aligned(16))) __bf16 Bs[128 * 32];
  const int K = 512;
  int n0 = blockIdx.x * 128, m0 = blockIdx.y * 128;
  int z = blockIdx.z;
  Bt += (size_t)z * bstride_bt;
  int tid = threadIdx.x, wave = tid >> 6, lane = tid & 63;
  int fr = lane & 15, fq = lane >> 4;
  int wm = (wave >> 1) * 64, wn = (wave & 1) * 64;
  f32x4 acc[4][4] = {};
  int o0_ = (wave * 2) * 1024 + lane * 16;
  int o1_ = o0_ + 1024;
  int r0 = o0_ >> 6, cb0 = o0_ & 63;
  int r1 = o1_ >> 6, cb1 = o1_ & 63;
  const char* Ap = (const char*)A;
  const char* Bp = (const char*)Bt;
  for (int k0 = 0; k0 < K; k0 += 32) {
    __syncthreads();
    gload16(Ap + ((size_t)(m0 + r0) * K + k0) * 2 + cb0, (char*)As + (wave * 2) * 1024);
    gload16(Ap + ((size_t)(m0 + r1) * K + k0) * 2 + cb1, (char*)As + (wave * 2 + 1) * 1024);
    gload16(Bp + ((size_t)(n0 + r0) * K + k0) * 2 + cb0, (char*)Bs + (wave * 2) * 1024);
    gload16(Bp + ((size_t)(n0 + r1) * K + k0) * 2 + cb1, (char*)Bs + (wave * 2 + 1) * 1024);
    __syncthreads();
    bf16x8 af[4], bfr[4];
#pragma unroll
    for (int mi = 0; mi < 4; mi++)
      af[mi] = *reinterpret_cast<const bf16x8*>((const char*)As + (wm + mi * 16 + fr) * 64 + fq * 16);
#pragma unroll
    for (int ni = 0; ni < 4; ni++)
      bfr[ni] = *reinterpret_cast<const bf16x8*>((const char*)Bs + (wn + ni * 16 + fr) * 64 + fq * 16);
#pragma unroll
    for (int mi = 0; mi < 4; mi++)
#pragma unroll
      for (int ni = 0; ni < 4; ni++)
        acc[mi][ni] = mfma16(af[mi], bfr[ni], acc[mi][ni]);
  }
  if (MODE == 0) {
#pragma unroll
    for (int mi = 0; mi < 4; mi++)
#pragma unroll
      for (int i = 0; i < 4; i++) {
        int row = m0 + wm + mi * 16 + fq * 4 + i;
#pragma unroll
        for (int ni = 0; ni < 4; ni++)
          Cb[(size_t)row * ldc + n0 + wn + ni * 16 + fr] = (__bf16)acc[mi][ni][i];
      }
  } else {
    float* Co = Cf + (size_t)z * bstride_c;
    const float* Xr = Xres + (size_t)z * bstride_c;
#pragma unroll
    for (int mi = 0; mi < 4; mi++)
#pragma unroll
      for (int i = 0; i < 4; i++) {
        int row = m0 + wm + mi * 16 + fq * 4 + i;
#pragma unroll
        for (int ni = 0; ni < 4; ni++) {
          size_t idx = (size_t)row * ldc + n0 + wn + ni * 16 + fr;
          Co[idx] = acc[mi][ni][i] + Xr[idx];
        }
      }
  }
}

// ---------------- pixnorm: h[16384][1536] -> Q,K [bh][s][d], Vt [bh][d][s] ----
// block = 3 waves (q/k/v group per wave), lane = token within 64-token tile.
__global__ __launch_bounds__(192) void pixnorm_k(const __bf16* __restrict__ h,
                                                 __bf16* __restrict__ Q,
                                                 __bf16* __restrict__ Kq,
                                                 __bf16* __restrict__ Vt) {
  int bid = blockIdx.x;                  // 2048 = 128 bh * 16 stile
  int stile = bid & 15, bh = bid >> 4;
  int wave = threadIdx.x >> 6, lane = threadIdx.x & 63;
  int b = bh >> 3, hd = bh & 7;
  int tok = stile * 64 + lane;
  const __bf16* src = h + ((size_t)(b * 1024 + tok)) * 1536 + hd * 192 + wave * 64;
  bf16x8 v[8];
#pragma unroll
  for (int i = 0; i < 8; i++) v[i] = *reinterpret_cast<const bf16x8*>(src + i * 8);
  float ss = 0.f;
#pragma unroll
  for (int i = 0; i < 8; i++)
#pragma unroll
    for (int j = 0; j < 8; j++) {
      float f = (float)v[i][j];
      ss += f * f;
    }
  float norm = rsqrtf(ss * (1.0f / 64.0f) + 1e-8f);
  if (wave == 0) norm *= 0.125f;  // fold SCALE^2 = 1/8 into Q
#pragma unroll
  for (int i = 0; i < 8; i++)
#pragma unroll
    for (int j = 0; j < 8; j++) v[i][j] = (__bf16)((float)v[i][j] * norm);
  if (wave == 0) {
    __bf16* dst = Q + ((size_t)bh * 1024 + tok) * 64;
#pragma unroll
    for (int i = 0; i < 8; i++) *reinterpret_cast<bf16x8*>(dst + i * 8) = v[i];
  } else if (wave == 1) {
    __bf16* dst = Kq + ((size_t)bh * 1024 + tok) * 64;
#pragma unroll
    for (int i = 0; i < 8; i++) *reinterpret_cast<bf16x8*>(dst + i * 8) = v[i];
  } else {
    // transposed store: lane owns its token's full row -> coalesced per-d stores
    __bf16* dst = Vt + (size_t)bh * 64 * 1024 + stile * 64 + lane;
#pragma unroll
    for (int d = 0; d < 64; d++) dst[(size_t)d * 1024] = v[d >> 3][d & 7];
  }
}

// ---------------- flash attention: per (bh, 64-row q tile) ----------------
__global__ __launch_bounds__(256) void attn_k(const __bf16* __restrict__ Q,
                                              const __bf16* __restrict__ Kb,
                                              const __bf16* __restrict__ Vt,
                                              __bf16* __restrict__ Res) {
  __shared__ __attribute__((aligned(16))) __bf16 Ks[64 * 64];
  __shared__ __attribute__((aligned(16))) __bf16 Vs[64 * 64];   // Vt tile: [d][sk]
  __shared__ __attribute__((aligned(16))) __bf16 Pl[4][16 * 64];
  int bid = blockIdx.x;                  // 2048 = 128 bh * 16 qt
  int qt = bid & 15, bh = bid >> 4;
  int wave = threadIdx.x >> 6, lane = threadIdx.x & 63;
  int fr = lane & 15, fq = lane >> 4;
  const __bf16* Qb = Q + (size_t)bh * 1024 * 64;
  const char* Kbase = (const char*)(Kb + (size_t)bh * 1024 * 64);
  const char* Vbase = (const char*)(Vt + (size_t)bh * 64 * 1024);
  bf16x8 qf[2];
#pragma unroll
  for (int kk = 0; kk < 2; kk++)
    qf[kk] = *reinterpret_cast<const bf16x8*>(
        Qb + (size_t)(qt * 64 + wave * 16 + fr) * 64 + kk * 32 + fq * 8);
  f32x4 oa[4] = {};
  float m_i[4], l_i[4];
#pragma unroll
  for (int i = 0; i < 4; i++) {
    m_i[i] = -1e30f;
    l_i[i] = 0.f;
  }
  int so0 = (wave * 2) * 1024 + lane * 16;
  int so1 = so0 + 1024;
  for (int kt = 0; kt < 16; kt++) {
    __syncthreads();
    gload16(Kbase + (size_t)kt * 8192 + so0, (char*)Ks + (wave * 2) * 1024);
    gload16(Kbase + (size_t)kt * 8192 + so1, (char*)Ks + (wave * 2 + 1) * 1024);
    gload16(Vbase + (size_t)(so0 >> 7) * 2048 + kt * 128 + (so0 & 127),
            (char*)Vs + (wave * 2) * 1024);
    gload16(Vbase + (size_t)(so1 >> 7) * 2048 + kt * 128 + (so1 & 127),
            (char*)Vs + (wave * 2 + 1) * 1024);
    __syncthreads();
    // S = Q K^T  (16 q-rows x 64 k-cols per wave)
    f32x4 sa[4] = {};
#pragma unroll
    for (int ni = 0; ni < 4; ni++)
#pragma unroll
      for (int kk = 0; kk < 2; kk++) {
        bf16x8 kf = *reinterpret_cast<const bf16x8*>(
            (const char*)Ks + (ni * 16 + fr) * 128 + kk * 64 + fq * 16);
        sa[ni] = mfma16(qf[kk], kf, sa[ni]);
      }
    // online softmax (rows owned by this lane's fq-group)
    float p[4][4];
#pragma unroll
    for (int i = 0; i < 4; i++) {
      float tm = fmaxf(fmaxf(sa[0][i], sa[1][i]), fmaxf(sa[2][i], sa[3][i]));
#pragma unroll
      for (int off = 1; off < 16; off <<= 1) tm = fmaxf(tm, __shfl_xor(tm, off));
      float mn = fmaxf(m_i[i], tm);
      float alpha = __expf(m_i[i] - mn);
      m_i[i] = mn;
      float rs = 0.f;
#pragma unroll
      for (int ni = 0; ni < 4; ni++) {
        p[ni][i] = __expf(sa[ni][i] - mn);
        rs += p[ni][i];
      }
#pragma unroll
      for (int off = 1; off < 16; off <<= 1) rs += __shfl_xor(rs, off);
      l_i[i] = l_i[i] * alpha + rs;
#pragma unroll
      for (int nd = 0; nd < 4; nd++) oa[nd][i] *= alpha;
    }
    // P -> LDS (per-wave region), then O += P V
#pragma unroll
    for (int ni = 0; ni < 4; ni++)
#pragma unroll
      for (int i = 0; i < 4; i++)
        Pl[wave][(fq * 4 + i) * 64 + ni * 16 + fr] = (__bf16)p[ni][i];
#pragma unroll
    for (int nd = 0; nd < 4; nd++)
#pragma unroll
      for (int kk2 = 0; kk2 < 2; kk2++) {
        bf16x8 pa = *reinterpret_cast<const bf16x8*>(
            (const char*)&Pl[wave][0] + fr * 128 + kk2 * 64 + fq * 16);
        bf16x8 vb = *reinterpret_cast<const bf16x8*>(
            (const char*)Vs + (nd * 16 + fr) * 128 + kk2 * 64 + fq * 16);
        oa[nd] = mfma16(pa, vb, oa[nd]);
      }
  }
  int b = bh >> 3, hd = bh & 7;
#pragma unroll
  for (int nd = 0; nd < 4; nd++)
#pragma unroll
    for (int i = 0; i < 4; i++) {
      int row = qt * 64 + wave * 16 + fq * 4 + i;
      float val = oa[nd][i] / l_i[i];
      Res[((size_t)(b * 1024 + row)) * 512 + hd * 64 + nd * 16 + fr] = (__bf16)val;
    }
}

// ---------------- launch ----------------
extern "C" void kernel_launch(void* const* d_in, const int* in_sizes, int n_in,
                              void* d_out, int out_size, void* d_ws, size_t ws_size,
                              hipStream_t stream) {
  const float* x = (const float*)d_in[0];
  const float* wp = (const float*)d_in[1];
  const float* wo = (const float*)d_in[2];
  float* out = (float*)d_out;
  char* w = (char*)d_ws;
  // workspace layout (bytes):
  __bf16* wpb = (__bf16*)(w);                    // 1536*512*2      = 1,572,864
  __bf16* wob = (__bf16*)(w + 1572864);          // 512*512*2       =   524,288
  __bf16* xt = (__bf16*)(w + 2097152);           // 16384*512*2     = 16,777,216
  __bf16* hb = (__bf16*)(w + 18874368);          // 16384*1536*2    = 50,331,648
  __bf16* Qb = (__bf16*)(w + 69206016);          // 128*1024*64*2   = 16,777,216
  __bf16* Kb = (__bf16*)(w + 85983232);          // same
  __bf16* Vtb = (__bf16*)(w + 102760448);        // same (transposed [bh][d][s])
  __bf16* resb = (__bf16*)(w + 119537664);       // 16384*512*2     = 16,777,216
  // total = 136,314,880 bytes

  cast_weights_k<<<4096, 256, 0, stream>>>(wp, wo, wpb, wob);
  transpose_x_k<<<dim3(16, 8, 16), 256, 0, stream>>>(x, xt);
  gemm_bt_k<0><<<dim3(12, 128, 1), 256, 0, stream>>>(xt, wpb, hb, nullptr, nullptr,
                                                     1536, 0, 0);
  pixnorm_k<<<2048, 192, 0, stream>>>(hb, Qb, Kb, Vtb);
  attn_k<<<2048, 256, 0, stream>>>(Qb, Kb, Vtb, resb);
  gemm_bt_k<1><<<dim3(8, 4, 16), 256, 0, stream>>>(wob, resb, nullptr, out, x, 1024,
                                                   1024L * 512, 512L * 1024);
}

// Round 2
// 168.967 us; speedup vs baseline: 1.4088x; 1.4088x over previous
//
#include <hip/hip_runtime.h>
#include <hip/hip_bf16.h>
#include <math.h>

typedef float f32x4 __attribute__((ext_vector_type(4)));
typedef __bf16 bf16x8 __attribute__((ext_vector_type(8)));
typedef __bf16 bf16x4 __attribute__((ext_vector_type(4)));

#define DEVFN static __device__ __forceinline__

DEVFN void gload16(const void* g, void* l) {
  __builtin_amdgcn_global_load_lds(
      (const __attribute__((address_space(1))) unsigned int*)g,
      (__attribute__((address_space(3))) unsigned int*)l, 16, 0, 0);
}

DEVFN f32x4 mfma16(bf16x8 a, bf16x8 b, f32x4 c) {
  return __builtin_amdgcn_mfma_f32_16x16x32_bf16(a, b, c, 0, 0, 0);
}

// ---------------- kernel 1: cast weights to bf16 ----------------
__global__ __launch_bounds__(256) void cast_weights_k(
    const float* __restrict__ wp, const float* __restrict__ wo,
    __bf16* __restrict__ wpb, __bf16* __restrict__ wob) {
  int i = blockIdx.x * 256 + threadIdx.x;
  if (i < 1536 * 512) {
    wpb[i] = (__bf16)wp[i];
  } else {
    int j = i - 1536 * 512;
    wob[j] = (__bf16)wo[j];
  }
}

// ---------------- kernel 2: transpose+cast x [B,C,S] f32 -> xt [B,S,C] bf16 ----
__global__ __launch_bounds__(256) void transpose_x_k(const float* __restrict__ x,
                                                     __bf16* __restrict__ xt) {
  __shared__ float tile[64][65];
  int b = blockIdx.z, c0 = blockIdx.y * 64, s0 = blockIdx.x * 64;
  int t = threadIdx.x;
  int r = t >> 2, q = (t & 3) << 4;
  const float* src = x + ((size_t)(b * 512 + c0 + r)) * 1024 + s0 + q;
#pragma unroll
  for (int i = 0; i < 4; i++) {
    float4 f = *reinterpret_cast<const float4*>(src + i * 4);
    tile[r][q + i * 4 + 0] = f.x;
    tile[r][q + i * 4 + 1] = f.y;
    tile[r][q + i * 4 + 2] = f.z;
    tile[r][q + i * 4 + 3] = f.w;
  }
  __syncthreads();
  bf16x8 o0, o1;
#pragma unroll
  for (int i = 0; i < 8; i++) o0[i] = (__bf16)tile[q + i][r];
#pragma unroll
  for (int i = 0; i < 8; i++) o1[i] = (__bf16)tile[q + 8 + i][r];
  __bf16* dst = xt + ((size_t)(b * 1024 + s0 + r)) * 512 + c0 + q;
  *reinterpret_cast<bf16x8*>(dst) = o0;
  *reinterpret_cast<bf16x8*>(dst + 8) = o1;
}

// ---------------- GEMM: C[m][n] = sum_k A[m][k]*Bt[n][k], K=512 ----------------
// LDS tiles [128 rows][64B] with 16B-slot swizzle: slot ^= (r ^ r>>2) & 3.
template <int MODE>
__global__ __launch_bounds__(256) void gemm_bt_k(
    const __bf16* __restrict__ A, const __bf16* __restrict__ Bt,
    __bf16* __restrict__ Cb, float* __restrict__ Cf, const float* __restrict__ Xres,
    int ldc, long bstride_bt, long bstride_c) {
  __shared__ __attribute__((aligned(16))) __bf16 As[128 * 32];
  __shared__ __attribute__((aligned(16))) __bf16 Bs[128 * 32];
  const int K = 512;
  int n0 = blockIdx.x * 128, m0 = blockIdx.y * 128;
  int z = blockIdx.z;
  Bt += (size_t)z * bstride_bt;
  int tid = threadIdx.x, wave = tid >> 6, lane = tid & 63;
  int fr = lane & 15, fq = lane >> 4;
  int wm = (wave >> 1) * 64, wn = (wave & 1) * 64;
  f32x4 acc[4][4] = {};
  int o0_ = (wave * 2) * 1024 + lane * 16;
  int o1_ = o0_ + 1024;
  int r0 = o0_ >> 6, cb0 = o0_ & 63;
  int r1 = o1_ >> 6, cb1 = o1_ & 63;
  int sw0 = ((r0 ^ (r0 >> 2)) & 3) << 4, sw1 = ((r1 ^ (r1 >> 2)) & 3) << 4;
  int sc0 = cb0 ^ sw0, sc1 = cb1 ^ sw1;
  int rdsw = (fr ^ (fr >> 2)) & 3;  // read-side slot xor (row bits == fr bits)
  const char* Ap = (const char*)A;
  const char* Bp = (const char*)Bt;
  for (int k0 = 0; k0 < K; k0 += 32) {
    __syncthreads();
    gload16(Ap + ((size_t)(m0 + r0) * K + k0) * 2 + sc0, (char*)As + o0_);
    gload16(Ap + ((size_t)(m0 + r1) * K + k0) * 2 + sc1, (char*)As + o1_);
    gload16(Bp + ((size_t)(n0 + r0) * K + k0) * 2 + sc0, (char*)Bs + o0_);
    gload16(Bp + ((size_t)(n0 + r1) * K + k0) * 2 + sc1, (char*)Bs + o1_);
    __syncthreads();
    bf16x8 af[4], bfr[4];
#pragma unroll
    for (int mi = 0; mi < 4; mi++)
      af[mi] = *reinterpret_cast<const bf16x8*>(
          (const char*)As + (wm + mi * 16 + fr) * 64 + ((fq ^ rdsw) << 4));
#pragma unroll
    for (int ni = 0; ni < 4; ni++)
      bfr[ni] = *reinterpret_cast<const bf16x8*>(
          (const char*)Bs + (wn + ni * 16 + fr) * 64 + ((fq ^ rdsw) << 4));
#pragma unroll
    for (int mi = 0; mi < 4; mi++)
#pragma unroll
      for (int ni = 0; ni < 4; ni++)
        acc[mi][ni] = mfma16(af[mi], bfr[ni], acc[mi][ni]);
  }
  if (MODE == 0) {
#pragma unroll
    for (int mi = 0; mi < 4; mi++)
#pragma unroll
      for (int i = 0; i < 4; i++) {
        int row = m0 + wm + mi * 16 + fq * 4 + i;
#pragma unroll
        for (int ni = 0; ni < 4; ni++)
          Cb[(size_t)row * ldc + n0 + wn + ni * 16 + fr] = (__bf16)acc[mi][ni][i];
      }
  } else {
    float* Co = Cf + (size_t)z * bstride_c;
    const float* Xr = Xres + (size_t)z * bstride_c;
#pragma unroll
    for (int mi = 0; mi < 4; mi++)
#pragma unroll
      for (int i = 0; i < 4; i++) {
        int row = m0 + wm + mi * 16 + fq * 4 + i;
#pragma unroll
        for (int ni = 0; ni < 4; ni++) {
          size_t idx = (size_t)row * ldc + n0 + wn + ni * 16 + fr;
          Co[idx] = acc[mi][ni][i] + Xr[idx];
        }
      }
  }
}

// ---------------- pixnorm: h[16384][1536] -> Q,K [bh][s][d], Vt [bh][d][s] ----
__global__ __launch_bounds__(192) void pixnorm_k(const __bf16* __restrict__ h,
                                                 __bf16* __restrict__ Q,
                                                 __bf16* __restrict__ Kq,
                                                 __bf16* __restrict__ Vt) {
  int bid = blockIdx.x;                  // 2048 = 128 bh * 16 stile
  int stile = bid & 15, bh = bid >> 4;
  int wave = threadIdx.x >> 6, lane = threadIdx.x & 63;
  int b = bh >> 3, hd = bh & 7;
  int tok = stile * 64 + lane;
  const __bf16* src = h + ((size_t)(b * 1024 + tok)) * 1536 + hd * 192 + wave * 64;
  bf16x8 v[8];
#pragma unroll
  for (int i = 0; i < 8; i++) v[i] = *reinterpret_cast<const bf16x8*>(src + i * 8);
  float ss = 0.f;
#pragma unroll
  for (int i = 0; i < 8; i++)
#pragma unroll
    for (int j = 0; j < 8; j++) {
      float f = (float)v[i][j];
      ss += f * f;
    }
  float norm = rsqrtf(ss * (1.0f / 64.0f) + 1e-8f);
  if (wave == 0) norm *= 0.125f;  // fold SCALE^2 = 1/8 into Q
#pragma unroll
  for (int i = 0; i < 8; i++)
#pragma unroll
    for (int j = 0; j < 8; j++) v[i][j] = (__bf16)((float)v[i][j] * norm);
  if (wave == 0) {
    __bf16* dst = Q + ((size_t)bh * 1024 + tok) * 64;
#pragma unroll
    for (int i = 0; i < 8; i++) *reinterpret_cast<bf16x8*>(dst + i * 8) = v[i];
  } else if (wave == 1) {
    __bf16* dst = Kq + ((size_t)bh * 1024 + tok) * 64;
#pragma unroll
    for (int i = 0; i < 8; i++) *reinterpret_cast<bf16x8*>(dst + i * 8) = v[i];
  } else {
    __bf16* dst = Vt + (size_t)bh * 64 * 1024 + stile * 64 + lane;
#pragma unroll
    for (int d = 0; d < 64; d++) dst[(size_t)d * 1024] = v[d >> 3][d & 7];
  }
}

// ---------------- flash attention (swapped QK^T, in-register P) ----------------
// Per block: one bh, 64 q-rows (4 waves x 16 q). K/V tiles 64 x 64, double-buffered.
// LDS tiles are [64 rows][128B], 16B-slot swizzle: slot ^= (row & 7).
__global__ __launch_bounds__(256) void attn_k(const __bf16* __restrict__ Q,
                                              const __bf16* __restrict__ Kb,
                                              const __bf16* __restrict__ Vt,
                                              __bf16* __restrict__ Res) {
  __shared__ __attribute__((aligned(16))) char lds[32768];
  int bid = blockIdx.x;                  // 2048 = 128 bh * 16 qt
  int qt = bid & 15, bh = bid >> 4;
  int wave = threadIdx.x >> 6, lane = threadIdx.x & 63;
  int fr = lane & 15, fq = lane >> 4;
  const __bf16* Qb = Q + (size_t)bh * 1024 * 64;
  const char* Kbase = (const char*)(Kb + (size_t)bh * 1024 * 64);
  const char* Vbase = (const char*)(Vt + (size_t)bh * 64 * 1024);
  // Q fragment (B-operand of swapped QK^T): lane holds Q[q0+fr][kk*32+fq*8 .. +7]
  bf16x8 qf[2];
#pragma unroll
  for (int kk = 0; kk < 2; kk++)
    qf[kk] = *reinterpret_cast<const bf16x8*>(
        Qb + (size_t)(qt * 64 + wave * 16 + fr) * 64 + kk * 32 + fq * 8);

  f32x4 oa[4] = {};
  float m_i = -1e30f, l_i = 0.f;  // per lane: one q-row (q = q0 + fr)

  // staging offsets (each wave loads 2x 1KB for K and V)
  int o0 = wave * 2048 + lane * 16;
  int o1 = o0 + 1024;
  int r0 = o0 >> 7, c0 = o0 & 127, r1 = o1 >> 7, c1 = o1 & 127;
  int s0 = c0 ^ ((r0 & 7) << 4), s1 = c1 ^ ((r1 & 7) << 4);
  int swr = (fr & 7) << 4;  // read-side xor

#define STAGE(kt_, buf_)                                                        \
  {                                                                             \
    char* ks_ = lds + (buf_)*8192;                                              \
    char* vs_ = lds + 16384 + (buf_)*8192;                                      \
    gload16(Kbase + (size_t)(kt_)*8192 + r0 * 128 + s0, ks_ + o0);              \
    gload16(Kbase + (size_t)(kt_)*8192 + r1 * 128 + s1, ks_ + o1);              \
    gload16(Vbase + (size_t)r0 * 2048 + (kt_)*128 + s0, vs_ + o0);              \
    gload16(Vbase + (size_t)r1 * 2048 + (kt_)*128 + s1, vs_ + o1);              \
  }

  STAGE(0, 0);
  __syncthreads();
  for (int kt = 0; kt < 16; kt++) {
    int cur = kt & 1;
    if (kt + 1 < 16) STAGE(kt + 1, cur ^ 1);
    const char* ksc = lds + cur * 8192;
    const char* vsc = lds + 16384 + cur * 8192;
    // S^T = K Q^T : sa[ni] holds S[k = ni*16 + fq*4 + i][q = fr]
    f32x4 sa[4] = {};
#pragma unroll
    for (int ni = 0; ni < 4; ni++)
#pragma unroll
      for (int kk = 0; kk < 2; kk++) {
        bf16x8 kf = *reinterpret_cast<const bf16x8*>(
            ksc + (ni * 16 + fr) * 128 + ((kk * 64 + fq * 16) ^ swr));
        sa[ni] = mfma16(kf, qf[kk], sa[ni]);
      }
    // online softmax: all 16 S values for q = q0+fr live in this lane (k spread
    // over fq groups) -> in-lane reduce + 2 shfl_xor over the fq bits.
    float tm = -1e30f;
#pragma unroll
    for (int ni = 0; ni < 4; ni++)
#pragma unroll
      for (int i = 0; i < 4; i++) tm = fmaxf(tm, sa[ni][i]);
    tm = fmaxf(tm, __shfl_xor(tm, 16));
    tm = fmaxf(tm, __shfl_xor(tm, 32));
    float mn = fmaxf(m_i, tm);
    float alpha = __expf(m_i - mn);
    m_i = mn;
    float p[4][4];
    float rs = 0.f;
#pragma unroll
    for (int ni = 0; ni < 4; ni++)
#pragma unroll
      for (int i = 0; i < 4; i++) {
        p[ni][i] = __expf(sa[ni][i] - mn);
        rs += p[ni][i];
      }
    rs += __shfl_xor(rs, 16);
    rs += __shfl_xor(rs, 32);
    l_i = l_i * alpha + rs;
#pragma unroll
    for (int nd = 0; nd < 4; nd++) oa[nd] *= alpha;
    // P packed in-register as PV B-fragment with k-permutation
    // pi(kk2,fq,j) = 32*kk2 + 16*(j>>2) + 4*fq + (j&3); V A-frag reads same pi.
    bf16x8 pb[2];
#pragma unroll
    for (int kk2 = 0; kk2 < 2; kk2++)
#pragma unroll
      for (int j = 0; j < 8; j++)
        pb[kk2][j] = (__bf16)p[2 * kk2 + (j >> 2)][j & 3];
#pragma unroll
    for (int nd = 0; nd < 4; nd++) {
      int vrow = (nd * 16 + fr) * 128;
#pragma unroll
      for (int kk2 = 0; kk2 < 2; kk2++) {
        int b0 = (64 * kk2 + 8 * fq) ^ swr;
        int b1 = (64 * kk2 + 32 + 8 * fq) ^ swr;
        bf16x4 vlo = *reinterpret_cast<const bf16x4*>(vsc + vrow + b0);
        bf16x4 vhi = *reinterpret_cast<const bf16x4*>(vsc + vrow + b1);
        bf16x8 vf = __builtin_shufflevector(vlo, vhi, 0, 1, 2, 3, 4, 5, 6, 7);
        oa[nd] = mfma16(vf, pb[kk2], oa[nd]);
      }
    }
    __syncthreads();
  }
  // epilogue: oa[nd]: O^T[d = nd*16 + fq*4 + i][q = fr]
  int b = bh >> 3, hd = bh & 7;
  int q = qt * 64 + wave * 16 + fr;
  float inv_l = 1.0f / l_i;
  __bf16* dst = Res + ((size_t)(b * 1024 + q)) * 512 + hd * 64 + fq * 4;
#pragma unroll
  for (int nd = 0; nd < 4; nd++) {
    bf16x4 ov;
#pragma unroll
    for (int i = 0; i < 4; i++) ov[i] = (__bf16)(oa[nd][i] * inv_l);
    *reinterpret_cast<bf16x4*>(dst + nd * 16) = ov;
  }
#undef STAGE
}

// ---------------- launch ----------------
extern "C" void kernel_launch(void* const* d_in, const int* in_sizes, int n_in,
                              void* d_out, int out_size, void* d_ws, size_t ws_size,
                              hipStream_t stream) {
  const float* x = (const float*)d_in[0];
  const float* wp = (const float*)d_in[1];
  const float* wo = (const float*)d_in[2];
  float* out = (float*)d_out;
  char* w = (char*)d_ws;
  __bf16* wpb = (__bf16*)(w);                    // 1,572,864
  __bf16* wob = (__bf16*)(w + 1572864);          //   524,288
  __bf16* xt = (__bf16*)(w + 2097152);           // 16,777,216
  __bf16* hb = (__bf16*)(w + 18874368);          // 50,331,648
  __bf16* Qb = (__bf16*)(w + 69206016);          // 16,777,216
  __bf16* Kb = (__bf16*)(w + 85983232);          // 16,777,216
  __bf16* Vtb = (__bf16*)(w + 102760448);        // 16,777,216 [bh][d][s]
  __bf16* resb = (__bf16*)(w + 119537664);       // 16,777,216

  cast_weights_k<<<4096, 256, 0, stream>>>(wp, wo, wpb, wob);
  transpose_x_k<<<dim3(16, 8, 16), 256, 0, stream>>>(x, xt);
  gemm_bt_k<0><<<dim3(12, 128, 1), 256, 0, stream>>>(xt, wpb, hb, nullptr, nullptr,
                                                     1536, 0, 0);
  pixnorm_k<<<2048, 192, 0, stream>>>(hb, Qb, Kb, Vtb);
  attn_k<<<2048, 256, 0, stream>>>(Qb, Kb, Vtb, resb);
  gemm_bt_k<1><<<dim3(8, 4, 16), 256, 0, stream>>>(wob, resb, nullptr, out, x, 1024,
                                                   1024L * 512, 512L * 1024);
}

// Round 3
// 156.880 us; speedup vs baseline: 1.5173x; 1.0770x over previous
//
#include <hip/hip_runtime.h>
#include <hip/hip_bf16.h>
#include <math.h>

typedef float f32x4 __attribute__((ext_vector_type(4)));
typedef __bf16 bf16x8 __attribute__((ext_vector_type(8)));
typedef __bf16 bf16x4 __attribute__((ext_vector_type(4)));

#define DEVFN static __device__ __forceinline__

DEVFN void gload16(const void* g, void* l) {
  __builtin_amdgcn_global_load_lds(
      (const __attribute__((address_space(1))) unsigned int*)g,
      (__attribute__((address_space(3))) unsigned int*)l, 16, 0, 0);
}

DEVFN f32x4 mfma16(bf16x8 a, bf16x8 b, f32x4 c) {
  return __builtin_amdgcn_mfma_f32_16x16x32_bf16(a, b, c, 0, 0, 0);
}

// ---------------- kernel 1: cast weights to bf16 ----------------
__global__ __launch_bounds__(256) void cast_weights_k(
    const float* __restrict__ wp, const float* __restrict__ wo,
    __bf16* __restrict__ wpb, __bf16* __restrict__ wob) {
  int i = blockIdx.x * 256 + threadIdx.x;
  if (i < 1536 * 512) {
    wpb[i] = (__bf16)wp[i];
  } else {
    int j = i - 1536 * 512;
    wob[j] = (__bf16)wo[j];
  }
}

// ---------------- kernel 2: transpose+cast x [B,C,S] f32 -> xt [B,S,C] bf16 ----
__global__ __launch_bounds__(256) void transpose_x_k(const float* __restrict__ x,
                                                     __bf16* __restrict__ xt) {
  __shared__ float tile[64][65];
  int b = blockIdx.z, c0 = blockIdx.y * 64, s0 = blockIdx.x * 64;
  int t = threadIdx.x;
  int r = t >> 2, q = (t & 3) << 4;
  const float* src = x + ((size_t)(b * 512 + c0 + r)) * 1024 + s0 + q;
#pragma unroll
  for (int i = 0; i < 4; i++) {
    float4 f = *reinterpret_cast<const float4*>(src + i * 4);
    tile[r][q + i * 4 + 0] = f.x;
    tile[r][q + i * 4 + 1] = f.y;
    tile[r][q + i * 4 + 2] = f.z;
    tile[r][q + i * 4 + 3] = f.w;
  }
  __syncthreads();
  bf16x8 o0, o1;
#pragma unroll
  for (int i = 0; i < 8; i++) o0[i] = (__bf16)tile[q + i][r];
#pragma unroll
  for (int i = 0; i < 8; i++) o1[i] = (__bf16)tile[q + 8 + i][r];
  __bf16* dst = xt + ((size_t)(b * 1024 + s0 + r)) * 512 + c0 + q;
  *reinterpret_cast<bf16x8*>(dst) = o0;
  *reinterpret_cast<bf16x8*>(dst + 8) = o1;
}

// ---------------- GEMM: C[m][n] = sum_k A[m][k]*Bt[n][k], K=512 ----------------
// MODE 2: fused pixnorm epilogue -> Q,K [bh][s][64] and Vt [bh][d][s] (LDS transpose)
// MODE 1: f32 C + residual Xres, per-batch z.
template <int MODE>
__global__ __launch_bounds__(256) void gemm_bt_k(
    const __bf16* __restrict__ A, const __bf16* __restrict__ Bt,
    float* __restrict__ Cf, const float* __restrict__ Xres,
    __bf16* __restrict__ Qo, __bf16* __restrict__ Ko, __bf16* __restrict__ Vto,
    int ldc, long bstride_bt, long bstride_c) {
  __shared__ __attribute__((aligned(16))) char smem[16384];  // As 8K | Bs 8K
  const int K = 512;
  int n0 = blockIdx.x * 128, m0 = blockIdx.y * 128;
  int z = blockIdx.z;
  Bt += (size_t)z * bstride_bt;
  int tid = threadIdx.x, wave = tid >> 6, lane = tid & 63;
  int fr = lane & 15, fq = lane >> 4;
  int wm = (wave >> 1) * 64, wn = (wave & 1) * 64;
  f32x4 acc[4][4] = {};
  int o0_ = (wave * 2) * 1024 + lane * 16;
  int o1_ = o0_ + 1024;
  int r0 = o0_ >> 6, cb0 = o0_ & 63;
  int r1 = o1_ >> 6, cb1 = o1_ & 63;
  int sw0 = ((r0 ^ (r0 >> 2)) & 3) << 4, sw1 = ((r1 ^ (r1 >> 2)) & 3) << 4;
  int sc0 = cb0 ^ sw0, sc1 = cb1 ^ sw1;
  int rdsw = (fr ^ (fr >> 2)) & 3;
  const char* Ap = (const char*)A;
  const char* Bp = (const char*)Bt;
  for (int k0 = 0; k0 < K; k0 += 32) {
    __syncthreads();
    gload16(Ap + ((size_t)(m0 + r0) * K + k0) * 2 + sc0, smem + o0_);
    gload16(Ap + ((size_t)(m0 + r1) * K + k0) * 2 + sc1, smem + o1_);
    gload16(Bp + ((size_t)(n0 + r0) * K + k0) * 2 + sc0, smem + 8192 + o0_);
    gload16(Bp + ((size_t)(n0 + r1) * K + k0) * 2 + sc1, smem + 8192 + o1_);
    __syncthreads();
    bf16x8 af[4], bfr[4];
#pragma unroll
    for (int mi = 0; mi < 4; mi++)
      af[mi] = *reinterpret_cast<const bf16x8*>(
          smem + (wm + mi * 16 + fr) * 64 + ((fq ^ rdsw) << 4));
#pragma unroll
    for (int ni = 0; ni < 4; ni++)
      bfr[ni] = *reinterpret_cast<const bf16x8*>(
          smem + 8192 + (wn + ni * 16 + fr) * 64 + ((fq ^ rdsw) << 4));
#pragma unroll
    for (int mi = 0; mi < 4; mi++)
#pragma unroll
      for (int ni = 0; ni < 4; ni++)
        acc[mi][ni] = mfma16(af[mi], bfr[ni], acc[mi][ni]);
  }
  if (MODE == 1) {
    float* Co = Cf + (size_t)z * bstride_c;
    const float* Xr = Xres + (size_t)z * bstride_c;
#pragma unroll
    for (int mi = 0; mi < 4; mi++)
#pragma unroll
      for (int i = 0; i < 4; i++) {
        int row = m0 + wm + mi * 16 + fq * 4 + i;
#pragma unroll
        for (int ni = 0; ni < 4; ni++) {
          size_t idx = (size_t)row * ldc + n0 + wn + ni * 16 + fr;
          Co[idx] = acc[mi][ni][i] + Xr[idx];
        }
      }
  } else {
    // ---- fused pixnorm epilogue ----
    int g0 = n0 + wn;            // 64-aligned global output-channel base
    int head = g0 / 192;         // 0..7
    int grp = (g0 >> 6) % 3;     // 0=q, 1=k, 2=v
    int b = m0 >> 10, sb = m0 & 1023;
    int bh = b * 8 + head;
    float nrm[4][4];
#pragma unroll
    for (int mi = 0; mi < 4; mi++)
#pragma unroll
      for (int i = 0; i < 4; i++) {
        float ss = 0.f;
#pragma unroll
        for (int ni = 0; ni < 4; ni++) ss += acc[mi][ni][i] * acc[mi][ni][i];
#pragma unroll
        for (int off = 1; off < 16; off <<= 1) ss += __shfl_xor(ss, off);
        float nv = rsqrtf(ss * (1.0f / 64.0f) + 1e-8f);
        // fold SCALE^2 = 1/8 and log2(e) into Q (attention works in exp2 domain)
        if (grp == 0) nv *= 0.18033688011112042f;
        nrm[mi][i] = nv;
      }
    if (grp < 2) {
      __bf16* dst = (grp == 0 ? Qo : Ko) + (size_t)bh * 65536;
#pragma unroll
      for (int mi = 0; mi < 4; mi++)
#pragma unroll
        for (int i = 0; i < 4; i++) {
          int s = sb + wm + mi * 16 + fq * 4 + i;
#pragma unroll
          for (int ni = 0; ni < 4; ni++)
            dst[(size_t)s * 64 + ni * 16 + fr] = (__bf16)(acc[mi][ni][i] * nrm[mi][i]);
        }
    }
    __syncthreads();
    if (grp == 2) {
      // normalized V -> LDS transpose tile [128 s][64 d], 4B-granule XOR swizzle
#pragma unroll
      for (int mi = 0; mi < 4; mi++)
#pragma unroll
        for (int i = 0; i < 4; i++) {
          int r = wm + mi * 16 + fq * 4 + i;
#pragma unroll
          for (int ni = 0; ni < 4; ni++) {
            int col2 = (2 * (ni * 16 + fr)) ^ ((r & 31) << 2);
            *(__bf16*)(smem + r * 128 + col2) = (__bf16)(acc[mi][ni][i] * nrm[mi][i]);
          }
        }
    }
    __syncthreads();
    if (grp == 2) {
      int sl = wm + lane;  // this wave's 64-s half of the 128-s tile
      __bf16* vdst = Vto + (size_t)bh * 65536 + sb + sl;
#pragma unroll 8
      for (int d = 0; d < 64; d++) {
        __bf16 v = *(const __bf16*)(smem + sl * 128 + ((2 * d) ^ ((sl & 31) << 2)));
        vdst[(size_t)d * 1024] = v;
      }
    }
  }
}

// ---------------- flash attention: no-max softmax in exp2 domain ----------------
// S = q-hat . k-hat / 8 is globally bounded in [-8, 8] (pixnorm), so exp2 never
// overflows: drop online-max entirely. Row-sum l via mfma(ones, P).
__global__ __launch_bounds__(256) void attn_k(const __bf16* __restrict__ Q,
                                              const __bf16* __restrict__ Kb,
                                              const __bf16* __restrict__ Vt,
                                              __bf16* __restrict__ Res) {
  __shared__ __attribute__((aligned(16))) char lds[32768];
  int bid = blockIdx.x;                  // 2048 = 128 bh * 16 qt
  int qt = bid & 15, bh = bid >> 4;
  int wave = threadIdx.x >> 6, lane = threadIdx.x & 63;
  int fr = lane & 15, fq = lane >> 4;
  const __bf16* Qb = Q + (size_t)bh * 1024 * 64;
  const char* Kbase = (const char*)(Kb + (size_t)bh * 1024 * 64);
  const char* Vbase = (const char*)(Vt + (size_t)bh * 64 * 1024);
  bf16x8 qf[2];
#pragma unroll
  for (int kk = 0; kk < 2; kk++)
    qf[kk] = *reinterpret_cast<const bf16x8*>(
        Qb + (size_t)(qt * 64 + wave * 16 + fr) * 64 + kk * 32 + fq * 8);

  bf16x8 ones;
#pragma unroll
  for (int j = 0; j < 8; j++) ones[j] = (__bf16)1.0f;

  f32x4 oa[4] = {};
  f32x4 lacc = {0.f, 0.f, 0.f, 0.f};

  int o0 = wave * 2048 + lane * 16;
  int o1 = o0 + 1024;
  int r0 = o0 >> 7, c0 = o0 & 127, r1 = o1 >> 7, c1 = o1 & 127;
  int s0 = c0 ^ ((r0 & 7) << 4), s1 = c1 ^ ((r1 & 7) << 4);
  int swr = (fr & 7) << 4;

#define STAGE(kt_, buf_)                                                        \
  {                                                                             \
    char* ks_ = lds + (buf_)*8192;                                              \
    char* vs_ = lds + 16384 + (buf_)*8192;                                      \
    gload16(Kbase + (size_t)(kt_)*8192 + r0 * 128 + s0, ks_ + o0);              \
    gload16(Kbase + (size_t)(kt_)*8192 + r1 * 128 + s1, ks_ + o1);              \
    gload16(Vbase + (size_t)r0 * 2048 + (kt_)*128 + s0, vs_ + o0);              \
    gload16(Vbase + (size_t)r1 * 2048 + (kt_)*128 + s1, vs_ + o1);              \
  }

  STAGE(0, 0);
  __syncthreads();
  for (int kt = 0; kt < 16; kt++) {
    int cur = kt & 1;
    if (kt + 1 < 16) STAGE(kt + 1, cur ^ 1);
    const char* ksc = lds + cur * 8192;
    const char* vsc = lds + 16384 + cur * 8192;
    // S^T = K Q^T : sa[ni] holds S[k = ni*16 + fq*4 + i][q = fr] (log2 units)
    f32x4 sa[4] = {};
#pragma unroll
    for (int ni = 0; ni < 4; ni++)
#pragma unroll
      for (int kk = 0; kk < 2; kk++) {
        bf16x8 kf = *reinterpret_cast<const bf16x8*>(
            ksc + (ni * 16 + fr) * 128 + ((kk * 64 + fq * 16) ^ swr));
        sa[ni] = mfma16(kf, qf[kk], sa[ni]);
      }
    // p = 2^S directly (bounded), pack to bf16 PV B-fragment with k-perm pi
    float p[4][4];
#pragma unroll
    for (int ni = 0; ni < 4; ni++)
#pragma unroll
      for (int i = 0; i < 4; i++) p[ni][i] = __builtin_exp2f(sa[ni][i]);
    bf16x8 pb[2];
#pragma unroll
    for (int kk2 = 0; kk2 < 2; kk2++)
#pragma unroll
      for (int j = 0; j < 8; j++)
        pb[kk2][j] = (__bf16)p[2 * kk2 + (j >> 2)][j & 3];
    // l += row-sums of P, on the matrix pipe (A = ones)
    lacc = mfma16(ones, pb[0], lacc);
    lacc = mfma16(ones, pb[1], lacc);
    // O^T += V^T P  (V A-frag reads same k-perm pi)
#pragma unroll
    for (int nd = 0; nd < 4; nd++) {
      int vrow = (nd * 16 + fr) * 128;
#pragma unroll
      for (int kk2 = 0; kk2 < 2; kk2++) {
        int b0 = (64 * kk2 + 8 * fq) ^ swr;
        int b1 = (64 * kk2 + 32 + 8 * fq) ^ swr;
        bf16x4 vlo = *reinterpret_cast<const bf16x4*>(vsc + vrow + b0);
        bf16x4 vhi = *reinterpret_cast<const bf16x4*>(vsc + vrow + b1);
        bf16x8 vf = __builtin_shufflevector(vlo, vhi, 0, 1, 2, 3, 4, 5, 6, 7);
        oa[nd] = mfma16(vf, pb[kk2], oa[nd]);
      }
    }
    __syncthreads();
  }
  // epilogue: oa[nd]: O^T[d = nd*16 + fq*4 + i][q = fr], l in lacc[0]
  int b = bh >> 3, hd = bh & 7;
  int q = qt * 64 + wave * 16 + fr;
  float inv_l = 1.0f / lacc[0];
  __bf16* dst = Res + ((size_t)(b * 1024 + q)) * 512 + hd * 64 + fq * 4;
#pragma unroll
  for (int nd = 0; nd < 4; nd++) {
    bf16x4 ov;
#pragma unroll
    for (int i = 0; i < 4; i++) ov[i] = (__bf16)(oa[nd][i] * inv_l);
    *reinterpret_cast<bf16x4*>(dst + nd * 16) = ov;
  }
#undef STAGE
}

// ---------------- launch ----------------
extern "C" void kernel_launch(void* const* d_in, const int* in_sizes, int n_in,
                              void* d_out, int out_size, void* d_ws, size_t ws_size,
                              hipStream_t stream) {
  const float* x = (const float*)d_in[0];
  const float* wp = (const float*)d_in[1];
  const float* wo = (const float*)d_in[2];
  float* out = (float*)d_out;
  char* w = (char*)d_ws;
  __bf16* wpb = (__bf16*)(w);                    // 1,572,864
  __bf16* wob = (__bf16*)(w + 1572864);          //   524,288
  __bf16* xt = (__bf16*)(w + 2097152);           // 16,777,216
  __bf16* Qb = (__bf16*)(w + 18874368);          // 16,777,216
  __bf16* Kb = (__bf16*)(w + 35651584);          // 16,777,216
  __bf16* Vtb = (__bf16*)(w + 52428800);         // 16,777,216 [bh][d][s]
  __bf16* resb = (__bf16*)(w + 69206016);        // 16,777,216

  cast_weights_k<<<4096, 256, 0, stream>>>(wp, wo, wpb, wob);
  transpose_x_k<<<dim3(16, 8, 16), 256, 0, stream>>>(x, xt);
  gemm_bt_k<2><<<dim3(12, 128, 1), 256, 0, stream>>>(xt, wpb, nullptr, nullptr,
                                                     Qb, Kb, Vtb, 1536, 0, 0);
  attn_k<<<2048, 256, 0, stream>>>(Qb, Kb, Vtb, resb);
  gemm_bt_k<1><<<dim3(8, 4, 16), 256, 0, stream>>>(wob, resb, out, x,
                                                   nullptr, nullptr, nullptr, 1024,
                                                   1024L * 512, 512L * 1024);
}

// Round 4
// 145.835 us; speedup vs baseline: 1.6322x; 1.0757x over previous
//
#include <hip/hip_runtime.h>
#include <hip/hip_bf16.h>
#include <math.h>

typedef float f32x4 __attribute__((ext_vector_type(4)));
typedef __bf16 bf16x8 __attribute__((ext_vector_type(8)));
typedef __bf16 bf16x4 __attribute__((ext_vector_type(4)));

#define DEVFN static __device__ __forceinline__

DEVFN void gload16(const void* g, void* l) {
  __builtin_amdgcn_global_load_lds(
      (const __attribute__((address_space(1))) unsigned int*)g,
      (__attribute__((address_space(3))) unsigned int*)l, 16, 0, 0);
}

DEVFN f32x4 mfma16(bf16x8 a, bf16x8 b, f32x4 c) {
  return __builtin_amdgcn_mfma_f32_16x16x32_bf16(a, b, c, 0, 0, 0);
}

// ---------------- kernel 1: cast weights to bf16 ----------------
__global__ __launch_bounds__(256) void cast_weights_k(
    const float* __restrict__ wp, const float* __restrict__ wo,
    __bf16* __restrict__ wpb, __bf16* __restrict__ wob) {
  int i = blockIdx.x * 256 + threadIdx.x;
  if (i < 1536 * 512) {
    wpb[i] = (__bf16)wp[i];
  } else {
    int j = i - 1536 * 512;
    wob[j] = (__bf16)wo[j];
  }
}

// ---------------- kernel 2: transpose+cast x [B,C,S] f32 -> xt [B,S,C] bf16 ----
__global__ __launch_bounds__(256) void transpose_x_k(const float* __restrict__ x,
                                                     __bf16* __restrict__ xt) {
  __shared__ float tile[64][65];
  int b = blockIdx.z, c0 = blockIdx.y * 64, s0 = blockIdx.x * 64;
  int t = threadIdx.x;
  int r = t >> 2, q = (t & 3) << 4;
  const float* src = x + ((size_t)(b * 512 + c0 + r)) * 1024 + s0 + q;
#pragma unroll
  for (int i = 0; i < 4; i++) {
    float4 f = *reinterpret_cast<const float4*>(src + i * 4);
    tile[r][q + i * 4 + 0] = f.x;
    tile[r][q + i * 4 + 1] = f.y;
    tile[r][q + i * 4 + 2] = f.z;
    tile[r][q + i * 4 + 3] = f.w;
  }
  __syncthreads();
  bf16x8 o0, o1;
#pragma unroll
  for (int i = 0; i < 8; i++) o0[i] = (__bf16)tile[q + i][r];
#pragma unroll
  for (int i = 0; i < 8; i++) o1[i] = (__bf16)tile[q + 8 + i][r];
  __bf16* dst = xt + ((size_t)(b * 1024 + s0 + r)) * 512 + c0 + q;
  *reinterpret_cast<bf16x8*>(dst) = o0;
  *reinterpret_cast<bf16x8*>(dst + 8) = o1;
}

// ---------------- GEMM: C[m][n] = sum_k A[m][k]*Bt[n][k], K=512, BK=64 --------
// LDS tiles [128 rows][128B], 16B-slot swizzle: byte ^= (row&7)<<4.
// MODE 2: fused pixnorm epilogue -> Q,K [bh][s][64] and Vt [bh][d][s].
// MODE 1: f32 C + residual Xres, per-batch z.
template <int MODE>
__global__ __launch_bounds__(256) void gemm_bt_k(
    const __bf16* __restrict__ A, const __bf16* __restrict__ Bt,
    float* __restrict__ Cf, const float* __restrict__ Xres,
    __bf16* __restrict__ Qo, __bf16* __restrict__ Ko, __bf16* __restrict__ Vto,
    int ldc, long bstride_bt, long bstride_c) {
  __shared__ __attribute__((aligned(16))) char smem[32768];  // As 16K | Bs 16K
  const int K = 512;
  int n0 = blockIdx.x * 128, m0 = blockIdx.y * 128;
  int z = blockIdx.z;
  Bt += (size_t)z * bstride_bt;
  int tid = threadIdx.x, wave = tid >> 6, lane = tid & 63;
  int fr = lane & 15, fq = lane >> 4;
  int wm = (wave >> 1) * 64, wn = (wave & 1) * 64;
  f32x4 acc[4][4] = {};
  int od[4], ro[4], sp[4];
#pragma unroll
  for (int i = 0; i < 4; i++) {
    od[i] = wave * 4096 + i * 1024 + lane * 16;
    ro[i] = od[i] >> 7;
    sp[i] = (od[i] & 127) ^ ((ro[i] & 7) << 4);
  }
  int rsw = (fr & 7) << 4;
  const char* Ap = (const char*)A;
  const char* Bp = (const char*)Bt;
  for (int k0 = 0; k0 < K; k0 += 64) {
    __syncthreads();
#pragma unroll
    for (int i = 0; i < 4; i++)
      gload16(Ap + (size_t)(m0 + ro[i]) * 1024 + k0 * 2 + sp[i], smem + od[i]);
#pragma unroll
    for (int i = 0; i < 4; i++)
      gload16(Bp + (size_t)(n0 + ro[i]) * 1024 + k0 * 2 + sp[i], smem + 16384 + od[i]);
    __syncthreads();
#pragma unroll
    for (int kk = 0; kk < 2; kk++) {
      bf16x8 af[4], bfr[4];
#pragma unroll
      for (int mi = 0; mi < 4; mi++)
        af[mi] = *reinterpret_cast<const bf16x8*>(
            smem + (wm + mi * 16 + fr) * 128 + ((kk * 64 + fq * 16) ^ rsw));
#pragma unroll
      for (int ni = 0; ni < 4; ni++)
        bfr[ni] = *reinterpret_cast<const bf16x8*>(
            smem + 16384 + (wn + ni * 16 + fr) * 128 + ((kk * 64 + fq * 16) ^ rsw));
      __builtin_amdgcn_s_setprio(1);
#pragma unroll
      for (int mi = 0; mi < 4; mi++)
#pragma unroll
        for (int ni = 0; ni < 4; ni++)
          acc[mi][ni] = mfma16(af[mi], bfr[ni], acc[mi][ni]);
      __builtin_amdgcn_s_setprio(0);
    }
  }
  if (MODE == 1) {
    float* Co = Cf + (size_t)z * bstride_c;
    const float* Xr = Xres + (size_t)z * bstride_c;
#pragma unroll
    for (int mi = 0; mi < 4; mi++)
#pragma unroll
      for (int i = 0; i < 4; i++) {
        int row = m0 + wm + mi * 16 + fq * 4 + i;
#pragma unroll
        for (int ni = 0; ni < 4; ni++) {
          size_t idx = (size_t)row * ldc + n0 + wn + ni * 16 + fr;
          Co[idx] = acc[mi][ni][i] + Xr[idx];
        }
      }
  } else {
    // ---- fused pixnorm epilogue ----
    int g0 = n0 + wn;            // 64-aligned global output-channel base
    int head = g0 / 192;         // 0..7
    int grp = (g0 >> 6) % 3;     // 0=q, 1=k, 2=v
    int b = m0 >> 10, sb = m0 & 1023;
    int bh = b * 8 + head;
    float nrm[4][4];
#pragma unroll
    for (int mi = 0; mi < 4; mi++)
#pragma unroll
      for (int i = 0; i < 4; i++) {
        float ss = 0.f;
#pragma unroll
        for (int ni = 0; ni < 4; ni++) ss += acc[mi][ni][i] * acc[mi][ni][i];
#pragma unroll
        for (int off = 1; off < 16; off <<= 1) ss += __shfl_xor(ss, off);
        float nv = rsqrtf(ss * (1.0f / 64.0f) + 1e-8f);
        // fold SCALE^2 = 1/8 and log2(e) into Q (attention works in exp2 domain)
        if (grp == 0) nv *= 0.18033688011112042f;
        nrm[mi][i] = nv;
      }
    if (grp < 2) {
      __bf16* dst = (grp == 0 ? Qo : Ko) + (size_t)bh * 65536;
#pragma unroll
      for (int mi = 0; mi < 4; mi++)
#pragma unroll
        for (int i = 0; i < 4; i++) {
          int s = sb + wm + mi * 16 + fq * 4 + i;
#pragma unroll
          for (int ni = 0; ni < 4; ni++)
            dst[(size_t)s * 64 + ni * 16 + fr] = (__bf16)(acc[mi][ni][i] * nrm[mi][i]);
        }
    }
    __syncthreads();
    if (grp == 2) {
      // normalized V -> LDS transpose tile [128 s][64 d], 4B-granule XOR swizzle
#pragma unroll
      for (int mi = 0; mi < 4; mi++)
#pragma unroll
        for (int i = 0; i < 4; i++) {
          int r = wm + mi * 16 + fq * 4 + i;
#pragma unroll
          for (int ni = 0; ni < 4; ni++) {
            int col2 = (2 * (ni * 16 + fr)) ^ ((r & 31) << 2);
            *(__bf16*)(smem + r * 128 + col2) = (__bf16)(acc[mi][ni][i] * nrm[mi][i]);
          }
        }
    }
    __syncthreads();
    if (grp == 2) {
      int sl = wm + lane;  // this wave's 64-s half of the 128-s tile
      __bf16* vdst = Vto + (size_t)bh * 65536 + sb + sl;
#pragma unroll 8
      for (int d = 0; d < 64; d++) {
        __bf16 v = *(const __bf16*)(smem + sl * 128 + ((2 * d) ^ ((sl & 31) << 2)));
        vdst[(size_t)d * 1024] = v;
      }
    }
  }
}

// ---------------- flash attention: QBLK=128, no-max exp2 softmax --------------
// Block: one bh, 128 q-rows (4 waves x 2 q-sets x 16 q). KV tiles 64x64 dbuf.
// K/V frags read once per tile, feed both q-sets. XCD swizzle clusters all 8
// q-tiles of one bh on one XCD for K/V L2 residency.
__global__ __launch_bounds__(256) void attn_k(const __bf16* __restrict__ Q,
                                              const __bf16* __restrict__ Kb,
                                              const __bf16* __restrict__ Vt,
                                              __bf16* __restrict__ Res) {
  __shared__ __attribute__((aligned(16))) char lds[32768];
  int p = blockIdx.x;                    // 1024 = 128 bh * 8 qt
  int v = (p & 7) * 128 + (p >> 3);      // XCD cluster swizzle (bijective)
  int qt = v & 7, bh = v >> 3;
  int wave = threadIdx.x >> 6, lane = threadIdx.x & 63;
  int fr = lane & 15, fq = lane >> 4;
  const __bf16* Qb = Q + (size_t)bh * 65536;
  const char* Kbase = (const char*)(Kb + (size_t)bh * 65536);
  const char* Vbase = (const char*)(Vt + (size_t)bh * 65536);
  bf16x8 qf[2][2];
#pragma unroll
  for (int qs = 0; qs < 2; qs++)
#pragma unroll
    for (int kk = 0; kk < 2; kk++)
      qf[qs][kk] = *reinterpret_cast<const bf16x8*>(
          Qb + (size_t)(qt * 128 + qs * 64 + wave * 16 + fr) * 64 + kk * 32 + fq * 8);

  bf16x8 ones;
#pragma unroll
  for (int j = 0; j < 8; j++) ones[j] = (__bf16)1.0f;

  f32x4 oa[2][4] = {};
  f32x4 lacc[2] = {};

  int o0 = wave * 2048 + lane * 16;
  int o1 = o0 + 1024;
  int r0 = o0 >> 7, c0 = o0 & 127, r1 = o1 >> 7, c1 = o1 & 127;
  int s0 = c0 ^ ((r0 & 7) << 4), s1 = c1 ^ ((r1 & 7) << 4);
  int swr = (fr & 7) << 4;

#define STAGE(kt_, buf_)                                                        \
  {                                                                             \
    char* ks_ = lds + (buf_)*8192;                                              \
    char* vs_ = lds + 16384 + (buf_)*8192;                                      \
    gload16(Kbase + (size_t)(kt_)*8192 + r0 * 128 + s0, ks_ + o0);              \
    gload16(Kbase + (size_t)(kt_)*8192 + r1 * 128 + s1, ks_ + o1);              \
    gload16(Vbase + (size_t)r0 * 2048 + (kt_)*128 + s0, vs_ + o0);              \
    gload16(Vbase + (size_t)r1 * 2048 + (kt_)*128 + s1, vs_ + o1);              \
  }

  STAGE(0, 0);
  __syncthreads();
  for (int kt = 0; kt < 16; kt++) {
    int cur = kt & 1;
    if (kt + 1 < 16) STAGE(kt + 1, cur ^ 1);
    const char* ksc = lds + cur * 8192;
    const char* vsc = lds + 16384 + cur * 8192;
    // S^T = K Q^T : sa[qs][ni] holds S[k = ni*16+fq*4+i][q = fr] (log2 units)
    f32x4 sa[2][4] = {};
    __builtin_amdgcn_s_setprio(1);
#pragma unroll
    for (int ni = 0; ni < 4; ni++) {
      bf16x8 kf0 = *reinterpret_cast<const bf16x8*>(
          ksc + (ni * 16 + fr) * 128 + ((fq * 16) ^ swr));
      bf16x8 kf1 = *reinterpret_cast<const bf16x8*>(
          ksc + (ni * 16 + fr) * 128 + ((64 + fq * 16) ^ swr));
#pragma unroll
      for (int qs = 0; qs < 2; qs++) {
        sa[qs][ni] = mfma16(kf0, qf[qs][0], sa[qs][ni]);
        sa[qs][ni] = mfma16(kf1, qf[qs][1], sa[qs][ni]);
      }
    }
    __builtin_amdgcn_s_setprio(0);
    // p = 2^S (bounded by pixnorm: |S'| <= 11.6), pack to PV B-frag (k-perm pi)
    bf16x8 pb[2][2];
#pragma unroll
    for (int qs = 0; qs < 2; qs++) {
      float pp[4][4];
#pragma unroll
      for (int ni = 0; ni < 4; ni++)
#pragma unroll
        for (int i = 0; i < 4; i++) pp[ni][i] = __builtin_exp2f(sa[qs][ni][i]);
#pragma unroll
      for (int kk2 = 0; kk2 < 2; kk2++)
#pragma unroll
        for (int j = 0; j < 8; j++)
          pb[qs][kk2][j] = (__bf16)pp[2 * kk2 + (j >> 2)][j & 3];
      lacc[qs] = mfma16(ones, pb[qs][0], lacc[qs]);
      lacc[qs] = mfma16(ones, pb[qs][1], lacc[qs]);
    }
    // O^T += V^T P  (V A-frag reads same k-perm pi; frags shared across qs)
    __builtin_amdgcn_s_setprio(1);
#pragma unroll
    for (int nd = 0; nd < 4; nd++) {
      int vrow = (nd * 16 + fr) * 128;
#pragma unroll
      for (int kk2 = 0; kk2 < 2; kk2++) {
        int b0 = (64 * kk2 + 8 * fq) ^ swr;
        int b1 = (64 * kk2 + 32 + 8 * fq) ^ swr;
        bf16x4 vlo = *reinterpret_cast<const bf16x4*>(vsc + vrow + b0);
        bf16x4 vhi = *reinterpret_cast<const bf16x4*>(vsc + vrow + b1);
        bf16x8 vf = __builtin_shufflevector(vlo, vhi, 0, 1, 2, 3, 4, 5, 6, 7);
#pragma unroll
        for (int qs = 0; qs < 2; qs++)
          oa[qs][nd] = mfma16(vf, pb[qs][kk2], oa[qs][nd]);
      }
    }
    __builtin_amdgcn_s_setprio(0);
    __syncthreads();
  }
  // epilogue: oa[qs][nd]: O^T[d = nd*16+fq*4+i][q = fr], l in lacc[qs][0]
  int b = bh >> 3, hd = bh & 7;
#pragma unroll
  for (int qs = 0; qs < 2; qs++) {
    int q = qt * 128 + qs * 64 + wave * 16 + fr;
    float inv_l = 1.0f / lacc[qs][0];
    __bf16* dst = Res + ((size_t)(b * 1024 + q)) * 512 + hd * 64 + fq * 4;
#pragma unroll
    for (int nd = 0; nd < 4; nd++) {
      bf16x4 ov;
#pragma unroll
      for (int i = 0; i < 4; i++) ov[i] = (__bf16)(oa[qs][nd][i] * inv_l);
      *reinterpret_cast<bf16x4*>(dst + nd * 16) = ov;
    }
  }
#undef STAGE
}

// ---------------- launch ----------------
extern "C" void kernel_launch(void* const* d_in, const int* in_sizes, int n_in,
                              void* d_out, int out_size, void* d_ws, size_t ws_size,
                              hipStream_t stream) {
  const float* x = (const float*)d_in[0];
  const float* wp = (const float*)d_in[1];
  const float* wo = (const float*)d_in[2];
  float* out = (float*)d_out;
  char* w = (char*)d_ws;
  __bf16* wpb = (__bf16*)(w);                    // 1,572,864
  __bf16* wob = (__bf16*)(w + 1572864);          //   524,288
  __bf16* xt = (__bf16*)(w + 2097152);           // 16,777,216
  __bf16* Qb = (__bf16*)(w + 18874368);          // 16,777,216
  __bf16* Kb = (__bf16*)(w + 35651584);          // 16,777,216
  __bf16* Vtb = (__bf16*)(w + 52428800);         // 16,777,216 [bh][d][s]
  __bf16* resb = (__bf16*)(w + 69206016);        // 16,777,216

  cast_weights_k<<<4096, 256, 0, stream>>>(wp, wo, wpb, wob);
  transpose_x_k<<<dim3(16, 8, 16), 256, 0, stream>>>(x, xt);
  gemm_bt_k<2><<<dim3(12, 128, 1), 256, 0, stream>>>(xt, wpb, nullptr, nullptr,
                                                     Qb, Kb, Vtb, 1536, 0, 0);
  attn_k<<<1024, 256, 0, stream>>>(Qb, Kb, Vtb, resb);
  gemm_bt_k<1><<<dim3(8, 4, 16), 256, 0, stream>>>(wob, resb, out, x,
                                                   nullptr, nullptr, nullptr, 1024,
                                                   1024L * 512, 512L * 1024);
}

// Round 5
// 140.806 us; speedup vs baseline: 1.6905x; 1.0357x over previous
//
#include <hip/hip_runtime.h>
#include <hip/hip_bf16.h>
#include <math.h>

typedef float f32x4 __attribute__((ext_vector_type(4)));
typedef __bf16 bf16x8 __attribute__((ext_vector_type(8)));
typedef __bf16 bf16x4 __attribute__((ext_vector_type(4)));
typedef unsigned u32x4 __attribute__((ext_vector_type(4)));

#define DEVFN static __device__ __forceinline__

DEVFN void gload16(const void* g, void* l) {
  __builtin_amdgcn_global_load_lds(
      (const __attribute__((address_space(1))) unsigned int*)g,
      (__attribute__((address_space(3))) unsigned int*)l, 16, 0, 0);
}

DEVFN f32x4 mfma16(bf16x8 a, bf16x8 b, f32x4 c) {
  return __builtin_amdgcn_mfma_f32_16x16x32_bf16(a, b, c, 0, 0, 0);
}

DEVFN unsigned cvtpk(float lo, float hi) {
  unsigned r;
  asm("v_cvt_pk_bf16_f32 %0, %1, %2" : "=v"(r) : "v"(lo), "v"(hi));
  return r;
}

// ---------------- kernel 1: cast weights to bf16 ----------------
__global__ __launch_bounds__(256) void cast_weights_k(
    const float* __restrict__ wp, const float* __restrict__ wo,
    __bf16* __restrict__ wpb, __bf16* __restrict__ wob) {
  int i = blockIdx.x * 256 + threadIdx.x;
  if (i < 1536 * 512) {
    wpb[i] = (__bf16)wp[i];
  } else {
    int j = i - 1536 * 512;
    wob[j] = (__bf16)wo[j];
  }
}

// ---------------- kernel 2: transpose+cast x [B,C,S] f32 -> xt [B,S,C] bf16 ----
__global__ __launch_bounds__(256) void transpose_x_k(const float* __restrict__ x,
                                                     __bf16* __restrict__ xt) {
  __shared__ float tile[64][65];
  int b = blockIdx.z, c0 = blockIdx.y * 64, s0 = blockIdx.x * 64;
  int t = threadIdx.x;
  int r = t >> 2, q = (t & 3) << 4;
  const float* src = x + ((size_t)(b * 512 + c0 + r)) * 1024 + s0 + q;
#pragma unroll
  for (int i = 0; i < 4; i++) {
    float4 f = *reinterpret_cast<const float4*>(src + i * 4);
    tile[r][q + i * 4 + 0] = f.x;
    tile[r][q + i * 4 + 1] = f.y;
    tile[r][q + i * 4 + 2] = f.z;
    tile[r][q + i * 4 + 3] = f.w;
  }
  __syncthreads();
  bf16x8 o0, o1;
#pragma unroll
  for (int i = 0; i < 8; i++) o0[i] = (__bf16)tile[q + i][r];
#pragma unroll
  for (int i = 0; i < 8; i++) o1[i] = (__bf16)tile[q + 8 + i][r];
  __bf16* dst = xt + ((size_t)(b * 1024 + s0 + r)) * 512 + c0 + q;
  *reinterpret_cast<bf16x8*>(dst) = o0;
  *reinterpret_cast<bf16x8*>(dst + 8) = o1;
}

// ---------------- GEMM: C[m][n] = sum_k A[m][k]*Bt[n][k], K=512, BK=64 --------
// LDS tiles [128 rows][128B], 16B-slot swizzle: byte ^= (row&7)<<4.
// MODE 2: fused pixnorm epilogue -> Q,K [bh][s][64] and Vp [bh][d][s-perm].
// MODE 1: f32 C + residual Xres, per-batch z.
template <int MODE>
__global__ __launch_bounds__(256) void gemm_bt_k(
    const __bf16* __restrict__ A, const __bf16* __restrict__ Bt,
    float* __restrict__ Cf, const float* __restrict__ Xres,
    __bf16* __restrict__ Qo, __bf16* __restrict__ Ko, __bf16* __restrict__ Vto,
    int ldc, long bstride_bt, long bstride_c) {
  __shared__ __attribute__((aligned(16))) char smem[32768];  // As 16K | Bs 16K
  const int K = 512;
  int n0 = blockIdx.x * 128, m0 = blockIdx.y * 128;
  int z = blockIdx.z;
  Bt += (size_t)z * bstride_bt;
  int tid = threadIdx.x, wave = tid >> 6, lane = tid & 63;
  int fr = lane & 15, fq = lane >> 4;
  int wm = (wave >> 1) * 64, wn = (wave & 1) * 64;
  f32x4 acc[4][4] = {};
  int od[4], ro[4], sp[4];
#pragma unroll
  for (int i = 0; i < 4; i++) {
    od[i] = wave * 4096 + i * 1024 + lane * 16;
    ro[i] = od[i] >> 7;
    sp[i] = (od[i] & 127) ^ ((ro[i] & 7) << 4);
  }
  int rsw = (fr & 7) << 4;
  const char* Ap = (const char*)A;
  const char* Bp = (const char*)Bt;
  for (int k0 = 0; k0 < K; k0 += 64) {
    __syncthreads();
#pragma unroll
    for (int i = 0; i < 4; i++)
      gload16(Ap + (size_t)(m0 + ro[i]) * 1024 + k0 * 2 + sp[i], smem + od[i]);
#pragma unroll
    for (int i = 0; i < 4; i++)
      gload16(Bp + (size_t)(n0 + ro[i]) * 1024 + k0 * 2 + sp[i], smem + 16384 + od[i]);
    __syncthreads();
#pragma unroll
    for (int kk = 0; kk < 2; kk++) {
      bf16x8 af[4], bfr[4];
#pragma unroll
      for (int mi = 0; mi < 4; mi++)
        af[mi] = *reinterpret_cast<const bf16x8*>(
            smem + (wm + mi * 16 + fr) * 128 + ((kk * 64 + fq * 16) ^ rsw));
#pragma unroll
      for (int ni = 0; ni < 4; ni++)
        bfr[ni] = *reinterpret_cast<const bf16x8*>(
            smem + 16384 + (wn + ni * 16 + fr) * 128 + ((kk * 64 + fq * 16) ^ rsw));
      __builtin_amdgcn_s_setprio(1);
#pragma unroll
      for (int mi = 0; mi < 4; mi++)
#pragma unroll
        for (int ni = 0; ni < 4; ni++)
          acc[mi][ni] = mfma16(af[mi], bfr[ni], acc[mi][ni]);
      __builtin_amdgcn_s_setprio(0);
    }
  }
  if (MODE == 1) {
    float* Co = Cf + (size_t)z * bstride_c;
    const float* Xr = Xres + (size_t)z * bstride_c;
#pragma unroll
    for (int mi = 0; mi < 4; mi++)
#pragma unroll
      for (int i = 0; i < 4; i++) {
        int row = m0 + wm + mi * 16 + fq * 4 + i;
#pragma unroll
        for (int ni = 0; ni < 4; ni++) {
          size_t idx = (size_t)row * ldc + n0 + wn + ni * 16 + fr;
          Co[idx] = acc[mi][ni][i] + Xr[idx];
        }
      }
  } else {
    // ---- fused pixnorm epilogue ----
    int g0 = n0 + wn;            // 64-aligned global output-channel base
    int head = g0 / 192;         // 0..7
    int grp = (g0 >> 6) % 3;     // 0=q, 1=k, 2=v
    int b = m0 >> 10, sb = m0 & 1023;
    int bh = b * 8 + head;
    float nrm[4][4];
#pragma unroll
    for (int mi = 0; mi < 4; mi++)
#pragma unroll
      for (int i = 0; i < 4; i++) {
        float ss = 0.f;
#pragma unroll
        for (int ni = 0; ni < 4; ni++) ss += acc[mi][ni][i] * acc[mi][ni][i];
#pragma unroll
        for (int off = 1; off < 16; off <<= 1) ss += __shfl_xor(ss, off);
        float nv = rsqrtf(ss * (1.0f / 64.0f) + 1e-8f);
        // fold SCALE^2 = 1/8 and log2(e) into Q (attention works in exp2 domain)
        if (grp == 0) nv *= 0.18033688011112042f;
        nrm[mi][i] = nv;
      }
    if (grp < 2) {
      __bf16* dst = (grp == 0 ? Qo : Ko) + (size_t)bh * 65536;
#pragma unroll
      for (int mi = 0; mi < 4; mi++)
#pragma unroll
        for (int i = 0; i < 4; i++) {
          int s = sb + wm + mi * 16 + fq * 4 + i;
#pragma unroll
          for (int ni = 0; ni < 4; ni++)
            dst[(size_t)s * 64 + ni * 16 + fr] = (__bf16)(acc[mi][ni][i] * nrm[mi][i]);
        }
    }
    __syncthreads();
    if (grp == 2) {
      // normalized V -> LDS transpose tile [128 s][64 d], 4B-granule XOR swizzle
#pragma unroll
      for (int mi = 0; mi < 4; mi++)
#pragma unroll
        for (int i = 0; i < 4; i++) {
          int r = wm + mi * 16 + fq * 4 + i;
#pragma unroll
          for (int ni = 0; ni < 4; ni++) {
            int col2 = (2 * (ni * 16 + fr)) ^ ((r & 31) << 2);
            *(__bf16*)(smem + r * 128 + col2) = (__bf16)(acc[mi][ni][i] * nrm[mi][i]);
          }
        }
    }
    __syncthreads();
    if (grp == 2) {
      int sl = wm + lane;  // this wave's 64-s half of the 128-s tile
      // permuted k-order within each 64-s tile: k = a*16+f*4+r stored at f*16+a*4+r
      int l = sl & 63;
      int pl = ((l >> 2) & 3) * 16 + (l >> 4) * 4 + (l & 3);
      __bf16* vdst = Vto + (size_t)bh * 65536 + sb + (sl & 64) + pl;
#pragma unroll 8
      for (int d = 0; d < 64; d++) {
        __bf16 v = *(const __bf16*)(smem + sl * 128 + ((2 * d) ^ ((sl & 31) << 2)));
        vdst[(size_t)d * 1024] = v;
      }
    }
  }
}

// ---------------- flash attention: QBLK=128, no-max exp2 softmax --------------
// Block: one bh, 128 q-rows (4 waves x 2 q-sets x 16 q). KV tiles 64x64 dbuf.
// V is stored k-permuted (pos = f*16+a*4+r <-> k = a*16+f*4+r) so the PV
// A-fragment is a single ds_read_b128; P packs into the matching B-frag order
// entirely in-register via v_cvt_pk_bf16_f32.
__global__ __launch_bounds__(256) void attn_k(const __bf16* __restrict__ Q,
                                              const __bf16* __restrict__ Kb,
                                              const __bf16* __restrict__ Vt,
                                              __bf16* __restrict__ Res) {
  __shared__ __attribute__((aligned(16))) char lds[32768];
  int p = blockIdx.x;                    // 1024 = 128 bh * 8 qt
  int v = (p & 7) * 128 + (p >> 3);      // XCD cluster swizzle (bijective)
  int qt = v & 7, bh = v >> 3;
  int wave = threadIdx.x >> 6, lane = threadIdx.x & 63;
  int fr = lane & 15, fq = lane >> 4;
  const __bf16* Qb = Q + (size_t)bh * 65536;
  const char* Kbase = (const char*)(Kb + (size_t)bh * 65536);
  const char* Vbase = (const char*)(Vt + (size_t)bh * 65536);
  bf16x8 qf[2][2];
#pragma unroll
  for (int qs = 0; qs < 2; qs++)
#pragma unroll
    for (int kk = 0; kk < 2; kk++)
      qf[qs][kk] = *reinterpret_cast<const bf16x8*>(
          Qb + (size_t)(qt * 128 + qs * 64 + wave * 16 + fr) * 64 + kk * 32 + fq * 8);

  bf16x8 ones;
#pragma unroll
  for (int j = 0; j < 8; j++) ones[j] = (__bf16)1.0f;

  f32x4 oa[2][4] = {};
  f32x4 lacc[2] = {};

  int o0 = wave * 2048 + lane * 16;
  int o1 = o0 + 1024;
  int r0 = o0 >> 7, c0 = o0 & 127, r1 = o1 >> 7, c1 = o1 & 127;
  int s0 = c0 ^ ((r0 & 7) << 4), s1 = c1 ^ ((r1 & 7) << 4);
  int swr = (fr & 7) << 4;

#define STAGE(kt_, buf_)                                                        \
  {                                                                             \
    char* ks_ = lds + (buf_)*8192;                                              \
    char* vs_ = lds + 16384 + (buf_)*8192;                                      \
    gload16(Kbase + (size_t)(kt_)*8192 + r0 * 128 + s0, ks_ + o0);              \
    gload16(Kbase + (size_t)(kt_)*8192 + r1 * 128 + s1, ks_ + o1);              \
    gload16(Vbase + (size_t)r0 * 2048 + (kt_)*128 + s0, vs_ + o0);              \
    gload16(Vbase + (size_t)r1 * 2048 + (kt_)*128 + s1, vs_ + o1);              \
  }

  STAGE(0, 0);
  __syncthreads();
  for (int kt = 0; kt < 16; kt++) {
    int cur = kt & 1;
    if (kt + 1 < 16) STAGE(kt + 1, cur ^ 1);
    const char* ksc = lds + cur * 8192;
    const char* vsc = lds + 16384 + cur * 8192;
    // S^T = K Q^T : sa[qs][ni] holds S[k = ni*16+fq*4+i][q = fr] (log2 units)
    f32x4 sa[2][4] = {};
    __builtin_amdgcn_s_setprio(1);
#pragma unroll
    for (int ni = 0; ni < 4; ni++) {
      bf16x8 kf0 = *reinterpret_cast<const bf16x8*>(
          ksc + (ni * 16 + fr) * 128 + ((fq * 16) ^ swr));
      bf16x8 kf1 = *reinterpret_cast<const bf16x8*>(
          ksc + (ni * 16 + fr) * 128 + ((64 + fq * 16) ^ swr));
#pragma unroll
      for (int qs = 0; qs < 2; qs++) {
        sa[qs][ni] = mfma16(kf0, qf[qs][0], sa[qs][ni]);
        sa[qs][ni] = mfma16(kf1, qf[qs][1], sa[qs][ni]);
      }
    }
    __builtin_amdgcn_s_setprio(0);
    // p = 2^S in-place (bounded by pixnorm: |S'| <= 11.6), then pack to the PV
    // B-frag order pi(kk2,fq,j) = 32*kk2+16*(j>>2)+4*fq+(j&3) via cvt_pk.
    bf16x8 pb[2][2];
#pragma unroll
    for (int qs = 0; qs < 2; qs++) {
#pragma unroll
      for (int ni = 0; ni < 4; ni++)
#pragma unroll
        for (int i = 0; i < 4; i++) sa[qs][ni][i] = __builtin_exp2f(sa[qs][ni][i]);
#pragma unroll
      for (int kk2 = 0; kk2 < 2; kk2++) {
        u32x4 u;
        u[0] = cvtpk(sa[qs][2 * kk2][0], sa[qs][2 * kk2][1]);
        u[1] = cvtpk(sa[qs][2 * kk2][2], sa[qs][2 * kk2][3]);
        u[2] = cvtpk(sa[qs][2 * kk2 + 1][0], sa[qs][2 * kk2 + 1][1]);
        u[3] = cvtpk(sa[qs][2 * kk2 + 1][2], sa[qs][2 * kk2 + 1][3]);
        pb[qs][kk2] = __builtin_bit_cast(bf16x8, u);
      }
      lacc[qs] = mfma16(ones, pb[qs][0], lacc[qs]);
      lacc[qs] = mfma16(ones, pb[qs][1], lacc[qs]);
    }
    // O^T += V^T P  (V A-frag: one b128 in permuted order; shared across qs)
    __builtin_amdgcn_s_setprio(1);
#pragma unroll
    for (int nd = 0; nd < 4; nd++) {
      int vrow = (nd * 16 + fr) * 128;
#pragma unroll
      for (int kk2 = 0; kk2 < 2; kk2++) {
        bf16x8 vf = *reinterpret_cast<const bf16x8*>(
            vsc + vrow + ((fq * 32 + kk2 * 16) ^ swr));
#pragma unroll
        for (int qs = 0; qs < 2; qs++)
          oa[qs][nd] = mfma16(vf, pb[qs][kk2], oa[qs][nd]);
      }
    }
    __builtin_amdgcn_s_setprio(0);
    __syncthreads();
  }
  // epilogue: oa[qs][nd]: O^T[d = nd*16+fq*4+i][q = fr], l in lacc[qs][0]
  int b = bh >> 3, hd = bh & 7;
#pragma unroll
  for (int qs = 0; qs < 2; qs++) {
    int q = qt * 128 + qs * 64 + wave * 16 + fr;
    float inv_l = 1.0f / lacc[qs][0];
    __bf16* dst = Res + ((size_t)(b * 1024 + q)) * 512 + hd * 64 + fq * 4;
#pragma unroll
    for (int nd = 0; nd < 4; nd++) {
      bf16x4 ov;
#pragma unroll
      for (int i = 0; i < 4; i++) ov[i] = (__bf16)(oa[qs][nd][i] * inv_l);
      *reinterpret_cast<bf16x4*>(dst + nd * 16) = ov;
    }
  }
#undef STAGE
}

// ---------------- launch ----------------
extern "C" void kernel_launch(void* const* d_in, const int* in_sizes, int n_in,
                              void* d_out, int out_size, void* d_ws, size_t ws_size,
                              hipStream_t stream) {
  const float* x = (const float*)d_in[0];
  const float* wp = (const float*)d_in[1];
  const float* wo = (const float*)d_in[2];
  float* out = (float*)d_out;
  char* w = (char*)d_ws;
  __bf16* wpb = (__bf16*)(w);                    // 1,572,864
  __bf16* wob = (__bf16*)(w + 1572864);          //   524,288
  __bf16* xt = (__bf16*)(w + 2097152);           // 16,777,216
  __bf16* Qb = (__bf16*)(w + 18874368);          // 16,777,216
  __bf16* Kb = (__bf16*)(w + 35651584);          // 16,777,216
  __bf16* Vtb = (__bf16*)(w + 52428800);         // 16,777,216 [bh][d][s-perm]
  __bf16* resb = (__bf16*)(w + 69206016);        // 16,777,216

  cast_weights_k<<<4096, 256, 0, stream>>>(wp, wo, wpb, wob);
  transpose_x_k<<<dim3(16, 8, 16), 256, 0, stream>>>(x, xt);
  gemm_bt_k<2><<<dim3(12, 128, 1), 256, 0, stream>>>(xt, wpb, nullptr, nullptr,
                                                     Qb, Kb, Vtb, 1536, 0, 0);
  attn_k<<<1024, 256, 0, stream>>>(Qb, Kb, Vtb, resb);
  gemm_bt_k<1><<<dim3(8, 4, 16), 256, 0, stream>>>(wob, resb, out, x,
                                                   nullptr, nullptr, nullptr, 1024,
                                                   1024L * 512, 512L * 1024);
}

// Round 6
// 123.943 us; speedup vs baseline: 1.9205x; 1.1361x over previous
//
#include <hip/hip_runtime.h>
#include <hip/hip_bf16.h>
#include <math.h>

typedef float f32x4 __attribute__((ext_vector_type(4)));
typedef __bf16 bf16x8 __attribute__((ext_vector_type(8)));
typedef __bf16 bf16x4 __attribute__((ext_vector_type(4)));
typedef unsigned u32x4 __attribute__((ext_vector_type(4)));

#define DEVFN static __device__ __forceinline__

DEVFN void gload16(const void* g, void* l) {
  __builtin_amdgcn_global_load_lds(
      (const __attribute__((address_space(1))) unsigned int*)g,
      (__attribute__((address_space(3))) unsigned int*)l, 16, 0, 0);
}

DEVFN f32x4 mfma16(bf16x8 a, bf16x8 b, f32x4 c) {
  return __builtin_amdgcn_mfma_f32_16x16x32_bf16(a, b, c, 0, 0, 0);
}

DEVFN unsigned cvtpk(float lo, float hi) {
  unsigned r;
  asm("v_cvt_pk_bf16_f32 %0, %1, %2" : "=v"(r) : "v"(lo), "v"(hi));
  return r;
}

// ---------------- kernel 1: cast weights to bf16 ----------------
__global__ __launch_bounds__(256) void cast_weights_k(
    const float* __restrict__ wp, const float* __restrict__ wo,
    __bf16* __restrict__ wpb, __bf16* __restrict__ wob) {
  int i = blockIdx.x * 256 + threadIdx.x;
  if (i < 1536 * 512) {
    wpb[i] = (__bf16)wp[i];
  } else {
    int j = i - 1536 * 512;
    wob[j] = (__bf16)wo[j];
  }
}

// ---------------- kernel 2: transpose+cast x [B,C,S] f32 -> xt [B,S,C] bf16 ----
__global__ __launch_bounds__(256) void transpose_x_k(const float* __restrict__ x,
                                                     __bf16* __restrict__ xt) {
  __shared__ float tile[64][65];
  int b = blockIdx.z, c0 = blockIdx.y * 64, s0 = blockIdx.x * 64;
  int t = threadIdx.x;
  int r = t >> 2, q = (t & 3) << 4;
  const float* src = x + ((size_t)(b * 512 + c0 + r)) * 1024 + s0 + q;
#pragma unroll
  for (int i = 0; i < 4; i++) {
    float4 f = *reinterpret_cast<const float4*>(src + i * 4);
    tile[r][q + i * 4 + 0] = f.x;
    tile[r][q + i * 4 + 1] = f.y;
    tile[r][q + i * 4 + 2] = f.z;
    tile[r][q + i * 4 + 3] = f.w;
  }
  __syncthreads();
  bf16x8 o0, o1;
#pragma unroll
  for (int i = 0; i < 8; i++) o0[i] = (__bf16)tile[q + i][r];
#pragma unroll
  for (int i = 0; i < 8; i++) o1[i] = (__bf16)tile[q + 8 + i][r];
  __bf16* dst = xt + ((size_t)(b * 1024 + s0 + r)) * 512 + c0 + q;
  *reinterpret_cast<bf16x8*>(dst) = o0;
  *reinterpret_cast<bf16x8*>(dst + 8) = o1;
}

// ---------------- GEMM: C[m][n] = sum_k A[m][k]*Bt[n][k], K=512, BK=64 --------
// LDS tiles [128 rows][128B], 16B-slot swizzle: byte ^= (row&7)<<4.
// MODE 2: fused pixnorm epilogue -> Q,K [bh][s][64] and Vp [bh][d][s-perm].
// MODE 1: f32 C + residual Xres, per-batch z.
template <int MODE>
__global__ __launch_bounds__(256) void gemm_bt_k(
    const __bf16* __restrict__ A, const __bf16* __restrict__ Bt,
    float* __restrict__ Cf, const float* __restrict__ Xres,
    __bf16* __restrict__ Qo, __bf16* __restrict__ Ko, __bf16* __restrict__ Vto,
    int ldc, long bstride_bt, long bstride_c) {
  __shared__ __attribute__((aligned(16))) char smem[32768];  // As 16K | Bs 16K
  const int K = 512;
  int n0 = blockIdx.x * 128, m0 = blockIdx.y * 128;
  int z = blockIdx.z;
  Bt += (size_t)z * bstride_bt;
  int tid = threadIdx.x, wave = tid >> 6, lane = tid & 63;
  int fr = lane & 15, fq = lane >> 4;
  int wm = (wave >> 1) * 64, wn = (wave & 1) * 64;
  f32x4 acc[4][4] = {};
  int od[4], ro[4], sp[4];
#pragma unroll
  for (int i = 0; i < 4; i++) {
    od[i] = wave * 4096 + i * 1024 + lane * 16;
    ro[i] = od[i] >> 7;
    sp[i] = (od[i] & 127) ^ ((ro[i] & 7) << 4);
  }
  int rsw = (fr & 7) << 4;
  const char* Ap = (const char*)A;
  const char* Bp = (const char*)Bt;
  for (int k0 = 0; k0 < K; k0 += 64) {
    __syncthreads();
#pragma unroll
    for (int i = 0; i < 4; i++)
      gload16(Ap + (size_t)(m0 + ro[i]) * 1024 + k0 * 2 + sp[i], smem + od[i]);
#pragma unroll
    for (int i = 0; i < 4; i++)
      gload16(Bp + (size_t)(n0 + ro[i]) * 1024 + k0 * 2 + sp[i], smem + 16384 + od[i]);
    __syncthreads();
#pragma unroll
    for (int kk = 0; kk < 2; kk++) {
      bf16x8 af[4], bfr[4];
#pragma unroll
      for (int mi = 0; mi < 4; mi++)
        af[mi] = *reinterpret_cast<const bf16x8*>(
            smem + (wm + mi * 16 + fr) * 128 + ((kk * 64 + fq * 16) ^ rsw));
#pragma unroll
      for (int ni = 0; ni < 4; ni++)
        bfr[ni] = *reinterpret_cast<const bf16x8*>(
            smem + 16384 + (wn + ni * 16 + fr) * 128 + ((kk * 64 + fq * 16) ^ rsw));
      __builtin_amdgcn_s_setprio(1);
#pragma unroll
      for (int mi = 0; mi < 4; mi++)
#pragma unroll
        for (int ni = 0; ni < 4; ni++)
          acc[mi][ni] = mfma16(af[mi], bfr[ni], acc[mi][ni]);
      __builtin_amdgcn_s_setprio(0);
    }
  }
  if (MODE == 1) {
    float* Co = Cf + (size_t)z * bstride_c;
    const float* Xr = Xres + (size_t)z * bstride_c;
#pragma unroll
    for (int mi = 0; mi < 4; mi++)
#pragma unroll
      for (int i = 0; i < 4; i++) {
        int row = m0 + wm + mi * 16 + fq * 4 + i;
#pragma unroll
        for (int ni = 0; ni < 4; ni++) {
          size_t idx = (size_t)row * ldc + n0 + wn + ni * 16 + fr;
          Co[idx] = acc[mi][ni][i] + Xr[idx];
        }
      }
  } else {
    // ---- fused pixnorm epilogue ----
    int g0 = n0 + wn;            // 64-aligned global output-channel base
    int head = g0 / 192;         // 0..7
    int grp = (g0 >> 6) % 3;     // 0=q, 1=k, 2=v
    int b = m0 >> 10, sb = m0 & 1023;
    int bh = b * 8 + head;
    float nrm[4][4];
#pragma unroll
    for (int mi = 0; mi < 4; mi++)
#pragma unroll
      for (int i = 0; i < 4; i++) {
        float ss = 0.f;
#pragma unroll
        for (int ni = 0; ni < 4; ni++) ss += acc[mi][ni][i] * acc[mi][ni][i];
#pragma unroll
        for (int off = 1; off < 16; off <<= 1) ss += __shfl_xor(ss, off);
        float nv = rsqrtf(ss * (1.0f / 64.0f) + 1e-8f);
        // fold SCALE^2 = 1/8 and log2(e) into Q (attention works in exp2 domain)
        if (grp == 0) nv *= 0.18033688011112042f;
        nrm[mi][i] = nv;
      }
    if (grp < 2) {
      __bf16* dst = (grp == 0 ? Qo : Ko) + (size_t)bh * 65536;
#pragma unroll
      for (int mi = 0; mi < 4; mi++)
#pragma unroll
        for (int i = 0; i < 4; i++) {
          int s = sb + wm + mi * 16 + fq * 4 + i;
#pragma unroll
          for (int ni = 0; ni < 4; ni++)
            dst[(size_t)s * 64 + ni * 16 + fr] = (__bf16)(acc[mi][ni][i] * nrm[mi][i]);
        }
    }
    __syncthreads();
    if (grp == 2) {
      // normalized V -> LDS transpose tile [128 s][64 d], 4B-granule XOR swizzle
#pragma unroll
      for (int mi = 0; mi < 4; mi++)
#pragma unroll
        for (int i = 0; i < 4; i++) {
          int r = wm + mi * 16 + fq * 4 + i;
#pragma unroll
          for (int ni = 0; ni < 4; ni++) {
            int col2 = (2 * (ni * 16 + fr)) ^ ((r & 31) << 2);
            *(__bf16*)(smem + r * 128 + col2) = (__bf16)(acc[mi][ni][i] * nrm[mi][i]);
          }
        }
    }
    __syncthreads();
    if (grp == 2) {
      int sl = wm + lane;  // this wave's 64-s half of the 128-s tile
      // permuted k-order within each 64-s tile: k = a*16+f*4+r stored at f*16+a*4+r
      int l = sl & 63;
      int pl = ((l >> 2) & 3) * 16 + (l >> 4) * 4 + (l & 3);
      __bf16* vdst = Vto + (size_t)bh * 65536 + sb + (sl & 64) + pl;
#pragma unroll 8
      for (int d = 0; d < 64; d++) {
        __bf16 v = *(const __bf16*)(smem + sl * 128 + ((2 * d) ^ ((sl & 31) << 2)));
        vdst[(size_t)d * 1024] = v;
      }
    }
  }
}

// ---------------- flash attention: QBLK=128, no-max exp2 softmax --------------
// Block: one bh, 128 q-rows (4 waves x 2 q-sets x 16 q). KV tiles 64x64 dbuf.
// V is stored k-permuted (pos = f*16+a*4+r <-> k = a*16+f*4+r) so the PV
// A-fragment is a single ds_read_b128; P packs into the matching B-frag order
// entirely in-register via v_cvt_pk_bf16_f32. exp2 is the RAW v_exp_f32
// (inputs bounded |s| <= 11.6 by pixnorm, so no denormal fixup needed).
// launch_bounds(256,4): 4 waves/SIMD target -> 128-VGPR budget (LDS caps
// occupancy at 4 blocks/CU anyway; 84-VGPR squeeze was costing VALU churn).
__global__ __launch_bounds__(256, 4) void attn_k(const __bf16* __restrict__ Q,
                                                 const __bf16* __restrict__ Kb,
                                                 const __bf16* __restrict__ Vt,
                                                 __bf16* __restrict__ Res) {
  __shared__ __attribute__((aligned(16))) char lds[32768];
  int p = blockIdx.x;                    // 1024 = 128 bh * 8 qt
  int v = (p & 7) * 128 + (p >> 3);      // XCD cluster swizzle (bijective)
  int qt = v & 7, bh = v >> 3;
  int wave = threadIdx.x >> 6, lane = threadIdx.x & 63;
  int fr = lane & 15, fq = lane >> 4;
  const __bf16* Qb = Q + (size_t)bh * 65536;
  const char* Kbase = (const char*)(Kb + (size_t)bh * 65536);
  const char* Vbase = (const char*)(Vt + (size_t)bh * 65536);
  bf16x8 qf[2][2];
#pragma unroll
  for (int qs = 0; qs < 2; qs++)
#pragma unroll
    for (int kk = 0; kk < 2; kk++)
      qf[qs][kk] = *reinterpret_cast<const bf16x8*>(
          Qb + (size_t)(qt * 128 + qs * 64 + wave * 16 + fr) * 64 + kk * 32 + fq * 8);

  bf16x8 ones;
#pragma unroll
  for (int j = 0; j < 8; j++) ones[j] = (__bf16)1.0f;

  f32x4 oa[2][4] = {};
  f32x4 lacc[2] = {};

  int o0 = wave * 2048 + lane * 16;
  int o1 = o0 + 1024;
  int r0 = o0 >> 7, c0 = o0 & 127, r1 = o1 >> 7, c1 = o1 & 127;
  int s0 = c0 ^ ((r0 & 7) << 4), s1 = c1 ^ ((r1 & 7) << 4);
  int swr = (fr & 7) << 4;

#define STAGE(kt_, buf_)                                                        \
  {                                                                             \
    char* ks_ = lds + (buf_)*8192;                                              \
    char* vs_ = lds + 16384 + (buf_)*8192;                                      \
    gload16(Kbase + (size_t)(kt_)*8192 + r0 * 128 + s0, ks_ + o0);              \
    gload16(Kbase + (size_t)(kt_)*8192 + r1 * 128 + s1, ks_ + o1);              \
    gload16(Vbase + (size_t)r0 * 2048 + (kt_)*128 + s0, vs_ + o0);              \
    gload16(Vbase + (size_t)r1 * 2048 + (kt_)*128 + s1, vs_ + o1);              \
  }

  STAGE(0, 0);
  __syncthreads();
  for (int kt = 0; kt < 16; kt++) {
    int cur = kt & 1;
    if (kt + 1 < 16) STAGE(kt + 1, cur ^ 1);
    const char* ksc = lds + cur * 8192;
    const char* vsc = lds + 16384 + cur * 8192;
    // S^T = K Q^T : sa[qs][ni] holds S[k = ni*16+fq*4+i][q = fr] (log2 units)
    f32x4 sa[2][4] = {};
    __builtin_amdgcn_s_setprio(1);
#pragma unroll
    for (int ni = 0; ni < 4; ni++) {
      bf16x8 kf0 = *reinterpret_cast<const bf16x8*>(
          ksc + (ni * 16 + fr) * 128 + ((fq * 16) ^ swr));
      bf16x8 kf1 = *reinterpret_cast<const bf16x8*>(
          ksc + (ni * 16 + fr) * 128 + ((64 + fq * 16) ^ swr));
#pragma unroll
      for (int qs = 0; qs < 2; qs++) {
        sa[qs][ni] = mfma16(kf0, qf[qs][0], sa[qs][ni]);
        sa[qs][ni] = mfma16(kf1, qf[qs][1], sa[qs][ni]);
      }
    }
    __builtin_amdgcn_s_setprio(0);
    // p = 2^S in-place (raw v_exp_f32; |S| <= 11.6 so no fixup needed), then
    // pack to the PV B-frag order pi(kk2,fq,j) = 32*kk2+16*(j>>2)+4*fq+(j&3).
    bf16x8 pb[2][2];
#pragma unroll
    for (int qs = 0; qs < 2; qs++) {
#pragma unroll
      for (int ni = 0; ni < 4; ni++)
#pragma unroll
        for (int i = 0; i < 4; i++)
          sa[qs][ni][i] = __builtin_amdgcn_exp2f(sa[qs][ni][i]);
#pragma unroll
      for (int kk2 = 0; kk2 < 2; kk2++) {
        u32x4 u;
        u[0] = cvtpk(sa[qs][2 * kk2][0], sa[qs][2 * kk2][1]);
        u[1] = cvtpk(sa[qs][2 * kk2][2], sa[qs][2 * kk2][3]);
        u[2] = cvtpk(sa[qs][2 * kk2 + 1][0], sa[qs][2 * kk2 + 1][1]);
        u[3] = cvtpk(sa[qs][2 * kk2 + 1][2], sa[qs][2 * kk2 + 1][3]);
        pb[qs][kk2] = __builtin_bit_cast(bf16x8, u);
      }
      lacc[qs] = mfma16(ones, pb[qs][0], lacc[qs]);
      lacc[qs] = mfma16(ones, pb[qs][1], lacc[qs]);
    }
    // O^T += V^T P  (V A-frag: one b128 in permuted order; shared across qs)
    __builtin_amdgcn_s_setprio(1);
#pragma unroll
    for (int nd = 0; nd < 4; nd++) {
      int vrow = (nd * 16 + fr) * 128;
#pragma unroll
      for (int kk2 = 0; kk2 < 2; kk2++) {
        bf16x8 vf = *reinterpret_cast<const bf16x8*>(
            vsc + vrow + ((fq * 32 + kk2 * 16) ^ swr));
#pragma unroll
        for (int qs = 0; qs < 2; qs++)
          oa[qs][nd] = mfma16(vf, pb[qs][kk2], oa[qs][nd]);
      }
    }
    __builtin_amdgcn_s_setprio(0);
    __syncthreads();
  }
  // epilogue: oa[qs][nd]: O^T[d = nd*16+fq*4+i][q = fr], l in lacc[qs][0]
  int b = bh >> 3, hd = bh & 7;
#pragma unroll
  for (int qs = 0; qs < 2; qs++) {
    int q = qt * 128 + qs * 64 + wave * 16 + fr;
    float inv_l = 1.0f / lacc[qs][0];
    __bf16* dst = Res + ((size_t)(b * 1024 + q)) * 512 + hd * 64 + fq * 4;
#pragma unroll
    for (int nd = 0; nd < 4; nd++) {
      bf16x4 ov;
#pragma unroll
      for (int i = 0; i < 4; i++) ov[i] = (__bf16)(oa[qs][nd][i] * inv_l);
      *reinterpret_cast<bf16x4*>(dst + nd * 16) = ov;
    }
  }
#undef STAGE
}

// ---------------- launch ----------------
extern "C" void kernel_launch(void* const* d_in, const int* in_sizes, int n_in,
                              void* d_out, int out_size, void* d_ws, size_t ws_size,
                              hipStream_t stream) {
  const float* x = (const float*)d_in[0];
  const float* wp = (const float*)d_in[1];
  const float* wo = (const float*)d_in[2];
  float* out = (float*)d_out;
  char* w = (char*)d_ws;
  __bf16* wpb = (__bf16*)(w);                    // 1,572,864
  __bf16* wob = (__bf16*)(w + 1572864);          //   524,288
  __bf16* xt = (__bf16*)(w + 2097152);           // 16,777,216
  __bf16* Qb = (__bf16*)(w + 18874368);          // 16,777,216
  __bf16* Kb = (__bf16*)(w + 35651584);          // 16,777,216
  __bf16* Vtb = (__bf16*)(w + 52428800);         // 16,777,216 [bh][d][s-perm]
  __bf16* resb = (__bf16*)(w + 69206016);        // 16,777,216

  cast_weights_k<<<4096, 256, 0, stream>>>(wp, wo, wpb, wob);
  transpose_x_k<<<dim3(16, 8, 16), 256, 0, stream>>>(x, xt);
  gemm_bt_k<2><<<dim3(12, 128, 1), 256, 0, stream>>>(xt, wpb, nullptr, nullptr,
                                                     Qb, Kb, Vtb, 1536, 0, 0);
  attn_k<<<1024, 256, 0, stream>>>(Qb, Kb, Vtb, resb);
  gemm_bt_k<1><<<dim3(8, 4, 16), 256, 0, stream>>>(wob, resb, out, x,
                                                   nullptr, nullptr, nullptr, 1024,
                                                   1024L * 512, 512L * 1024);
}